// Round 9
// baseline (343.563 us; speedup 1.0000x reference)
//
#include <hip/hip_runtime.h>
#include <hip/hip_bf16.h>

typedef __hip_bfloat16 bf16;
typedef __attribute__((ext_vector_type(8))) __bf16 bf16x8;
typedef __attribute__((ext_vector_type(4))) float f32x4;

#define MFMA16(a, b, c) __builtin_amdgcn_mfma_f32_16x16x32_bf16((a), (b), (c), 0, 0, 0)

#define BT 4096      // B*T rows
#define CE 2048      // embed dim
#define NQKV 3072    // q(2048) + k(512) + v(512)
#define TSEQ 2048
#define HD 128

// q pre-scale: 1/sqrt(128) * log2(e), folded into rope_rms's q output.
#define QSCALE (0.08838834764831845f * 1.4426950408889634f)
// fixed softmax max bound: ||q'||*||k|| = 128*QSCALE (Cauchy-Schwarz on
// RMS-normalized vectors). p = 2^(s' - M2) <= ~1, no online max needed.
#define M2 16.3222f

// ---------------------------------------------------------------------------
// async global->LDS 16B copy (one instruction, no VGPR round trip)
__device__ __forceinline__ void gld16(const void* g, void* l)
{
    __builtin_amdgcn_global_load_lds(
        (const __attribute__((address_space(1))) void*)g,
        (__attribute__((address_space(3))) void*)l, 16, 0, 0);
}

// ---------------------------------------------------------------------------
// Input-dtype detector (inputs are fp32; gate kept for safety).
__global__ void detect_dtype(const unsigned short* __restrict__ x, int* __restrict__ flag)
{
    __shared__ int cnt;
    if (threadIdx.x == 0) cnt = 0;
    __syncthreads();
    unsigned short w = x[2 * threadIdx.x];
    int e = (w >> 7) & 0xFF;
    atomicAdd(&cnt, (e >= 117 && e <= 130) ? 1 : 0);
    __syncthreads();
    if (threadIdx.x == 0) *flag = (cnt < 128) ? 1 : 0;
}

// Stage 8 elems (16B bf16) into LDS from bf16 or fp32 source (VGPR convert).
__device__ __forceinline__ void stage8(short* dst, const void* src, size_t eoff, bool f32)
{
    if (f32) {
        const float* s = (const float*)src + eoff;
        float4 f0 = *(const float4*)s;
        float4 f1 = *(const float4*)(s + 4);
        bf16x8 v;
        v[0] = (__bf16)f0.x; v[1] = (__bf16)f0.y; v[2] = (__bf16)f0.z; v[3] = (__bf16)f0.w;
        v[4] = (__bf16)f1.x; v[5] = (__bf16)f1.y; v[6] = (__bf16)f1.z; v[7] = (__bf16)f1.w;
        *(bf16x8*)dst = v;
    } else {
        *(uint4*)dst = *(const uint4*)((const bf16*)src + eoff);
    }
}

__device__ __forceinline__ float ldf(const void* p, int i, bool f32)
{
    return f32 ? ((const float*)p)[i] : __bfloat162float(((const bf16*)p)[i]);
}

// ---------------------------------------------------------------------------
// fp32 (or bf16) -> bf16 conversion, 8 elems/thread.
__global__ __launch_bounds__(256)
void conv_bf16(const void* __restrict__ src, bf16* __restrict__ dst,
               const int* __restrict__ flagp)
{
    const bool f = *flagp != 0;
    size_t i8 = (size_t)blockIdx.x * 256 + threadIdx.x;
    stage8((short*)(dst + i8 * 8), src, i8 * 8, f);
}

// ---------------------------------------------------------------------------
// Legacy 128^2 GEMM, kept ONLY as ws-constrained fallback (fp32-A staging).
__global__ __launch_bounds__(256)
void gemm_bt(const void* __restrict__ A, const bf16* __restrict__ W,
             void* __restrict__ C, int M, int N, int K, int lda,
             int aGate, int oGate, const int* __restrict__ flagp)
{
    __shared__ short As[128][32];
    __shared__ short Bs[128][32];

    const int f = *flagp;
    const bool aF = aGate && f, oF = oGate && f;

    const int tid   = threadIdx.x;
    const int lane  = tid & 63;
    const int wid   = tid >> 6;
    const int row16 = lane & 15;
    const int quad  = lane >> 4;
    const int wr    = wid >> 1;
    const int wc    = wid & 1;
    const int m0    = blockIdx.y * 128;
    const int n0    = blockIdx.x * 128;

    const int rl4 = wid * 16 + (lane >> 2);
    const int c8  = (lane & 3) * 8;

    f32x4 acc[4][4];
#pragma unroll
    for (int i = 0; i < 4; i++)
#pragma unroll
        for (int j = 0; j < 4; j++)
            acc[i][j] = (f32x4){0.f, 0.f, 0.f, 0.f};

    for (int k0 = 0; k0 < K; k0 += 32) {
#pragma unroll
        for (int i = 0; i < 2; i++) {
            int r = i * 64 + rl4;
            gld16(W + (size_t)(n0 + r) * K + k0 + c8, &Bs[r][c8]);
        }
        if (!aF) {
#pragma unroll
            for (int i = 0; i < 2; i++) {
                int r = i * 64 + rl4;
                gld16((const bf16*)A + (size_t)(m0 + r) * lda + k0 + c8, &As[r][c8]);
            }
        } else {
#pragma unroll
            for (int i = 0; i < 2; i++) {
                int c = i * 256 + tid;
                int row = c >> 2, col = (c & 3) << 3;
                stage8(&As[row][col], A, (size_t)(m0 + row) * lda + k0 + col, true);
            }
        }
        __syncthreads();

        bf16x8 af[4], bfv[4];
#pragma unroll
        for (int mi = 0; mi < 4; mi++)
            af[mi] = *(const bf16x8*)&As[wr * 64 + mi * 16 + row16][quad * 8];
#pragma unroll
        for (int ni = 0; ni < 4; ni++)
            bfv[ni] = *(const bf16x8*)&Bs[wc * 64 + ni * 16 + row16][quad * 8];
#pragma unroll
        for (int mi = 0; mi < 4; mi++)
#pragma unroll
            for (int ni = 0; ni < 4; ni++)
                acc[mi][ni] = MFMA16(af[mi], bfv[ni], acc[mi][ni]);
        __syncthreads();
    }

#pragma unroll
    for (int mi = 0; mi < 4; mi++) {
        int rowb = m0 + wr * 64 + mi * 16 + quad * 4;
#pragma unroll
        for (int ni = 0; ni < 4; ni++) {
            int col = n0 + wc * 64 + ni * 16 + row16;
#pragma unroll
            for (int r = 0; r < 4; r++) {
                size_t idx = (size_t)(rowb + r) * N + col;
                float  v   = acc[mi][ni][r];
                if (oF) ((float*)C)[idx] = v;
                else    ((bf16*)C)[idx]  = __float2bfloat16(v);
            }
        }
    }
}

// ---------------------------------------------------------------------------
// gemmQ (T3+T4 on top of verified gemmP pieces): BM=128 x BN=NI*64, BK=64,
// 512 thr / 8 waves (2M x 4N), THREE LDS buffers, 4 phases per K-tile,
// counted vmcnt once per tile.
//   Race-freedom: tile t reads buf t%3; stages during tile t write (t+2)%3
//   -- never the read buf nor (t+1)%3. The per-tile vmcnt(INFL) at the last
//   phase leaves only tile t+2's INFL loads in flight => tile t+1 proven
//   landed for every wave, then barrier.
//   Phase skeleton (m201): {ds_reads || stage -> s_barrier -> lgkmcnt(0) ->
//   setprio(1) MFMA setprio(0) -> s_barrier -> sched_barrier}.
//   T2: full-row XOR swizzle (phys16B = chunk ^ (row&7)) via pre-swizzled
//   global source. T1: bijective XCD swizzle (grids 512 / 256, %8==0).
//   gemm1: NI=3 (BN=192) -> grid 16x32 = 512 blocks = 2 clean full rounds.
//   gemm2: NI=4 (BN=256) -> grid  8x32 = 256 blocks = 1 full round.
// A bf16 [M][lda], W bf16 [N][K], C [M][N]. M%128==0, N%BN==0, K%64==0, K>=128.
template<int MI, int NI>
__global__ __launch_bounds__(512, 2)
void gemmQ(const bf16* __restrict__ A, const bf16* __restrict__ W,
           void* __restrict__ C, int M, int N, int K, int lda,
           int oGate, const int* __restrict__ flagp)
{
    constexpr int BM    = MI * 32;        // 128
    constexpr int BN    = NI * 64;        // 192 / 256
    constexpr int ATILE = BM * 128;       // bytes per 64-K tile
    constexpr int BTILE = BN * 128;
    constexpr int AUL   = BM / 64;        // 2 gld16/thread for A
    constexpr int BUL   = BN / 64;        // NI gld16/thread for B
    constexpr int INFL  = AUL + BUL;      // loads/tile = allowed in-flight

    __shared__ __bf16 As[3][BM][64];
    __shared__ __bf16 Bs[3][BN][64];

    const bool oF = oGate && (*flagp != 0);

    // XCD swizzle: bijective since total blocks % 8 == 0
    const int gx  = gridDim.x;
    const int lin = blockIdx.y * gx + blockIdx.x;
    const int cpx = (gx * gridDim.y) >> 3;
    const int swzid = (lin & 7) * cpx + (lin >> 3);
    const int bx = swzid % gx;
    const int by = swzid / gx;

    const int tid   = threadIdx.x;
    const int lane  = tid & 63;
    const int wid   = tid >> 6;
    const int row16 = lane & 15;
    const int quad  = lane >> 4;
    const int wr    = wid >> 2;           // 0..1
    const int wc    = wid & 3;            // 0..3
    const int m0    = by * BM;
    const int n0    = bx * BN;
    const int NT    = K >> 6;

    // staging: dest linear = slot + u*8192 + tid*16; row = u*64 + tid/8,
    // phys chunk = tid&7; global source supplies logical = phys ^ (row&7).
    const int srow = tid >> 3;
    const int sc8  = ((tid & 7) ^ (srow & 7)) * 8;
    const bf16* Ag = A + (size_t)(m0 + srow) * lda + sc8;
    const bf16* Bg = W + (size_t)(n0 + srow) * K   + sc8;
    char* const AsB = (char*)As;
    char* const BsB = (char*)Bs;
    const int sdst = tid * 16;

    auto stA = [&](int kt, int s) {
#pragma unroll
        for (int u = 0; u < AUL; ++u)
            gld16(Ag + (size_t)(u * 64) * lda + kt * 64,
                  AsB + s * ATILE + u * 8192 + sdst);
    };
    auto stB = [&](int kt, int s) {
#pragma unroll
        for (int u = 0; u < BUL; ++u)
            gld16(Bg + (size_t)(u * 64) * K + kt * 64,
                  BsB + s * BTILE + u * 8192 + sdst);
    };

    // fragment reads: phys = (kk*4+quad) ^ (row16&7)
    const int swz  = ((quad ^ (row16 & 7)) * 16);
    const int swz1 = (((4 + quad) ^ (row16 & 7)) * 16);
    const int aRow = wr * (MI * 16) + row16;
    const int bRow = wc * (NI * 16) + row16;

    auto ldA = [&](int sb, int mi, int kk) -> bf16x8 {
        return *(const bf16x8*)(AsB + sb + (aRow + mi * 16) * 128
                                + (kk ? swz1 : swz));
    };
    auto ldB = [&](int sb, int ni, int kk) -> bf16x8 {
        return *(const bf16x8*)(BsB + sb + (bRow + ni * 16) * 128
                                + (kk ? swz1 : swz));
    };

    f32x4 acc[MI][NI];
#pragma unroll
    for (int i = 0; i < MI; i++)
#pragma unroll
        for (int j = 0; j < NI; j++)
            acc[i][j] = (f32x4){0.f, 0.f, 0.f, 0.f};

    // prologue: tiles 0,1 -> slots 0,1; drain tile 0 (tile 1's INFL remain)
    stA(0, 0); stB(0, 0);
    stA(1, 1); stB(1, 1);
    if constexpr (INFL == 5) asm volatile("s_waitcnt vmcnt(5)" ::: "memory");
    else                     asm volatile("s_waitcnt vmcnt(6)" ::: "memory");
    __builtin_amdgcn_s_barrier();
    __builtin_amdgcn_sched_barrier(0);

    int rs = 0, ps = 2;
    for (int t = 0; t < NT; ++t) {
        const bool pf = (t + 2) < NT;
        const int ra  = rs * ATILE;
        const int rbo = rs * BTILE;

        bf16x8 bfr[NI], aa[2];

        // ---- phase 0: kk=0, mi 0..1; read B(kk0); stage A(t+2) ----
#pragma unroll
        for (int ni = 0; ni < NI; ni++) bfr[ni] = ldB(rbo, ni, 0);
        aa[0] = ldA(ra, 0, 0); aa[1] = ldA(ra, 1, 0);
        if (pf) stA(t + 2, ps);
        __builtin_amdgcn_s_barrier();
        asm volatile("s_waitcnt lgkmcnt(0)" ::: "memory");
        __builtin_amdgcn_s_setprio(1);
#pragma unroll
        for (int i = 0; i < 2; i++)
#pragma unroll
            for (int ni = 0; ni < NI; ni++)
                acc[i][ni] = MFMA16(aa[i], bfr[ni], acc[i][ni]);
        __builtin_amdgcn_s_setprio(0);
        __builtin_amdgcn_s_barrier();
        __builtin_amdgcn_sched_barrier(0);

        // ---- phase 1: kk=0, mi 2..3 ----
        aa[0] = ldA(ra, 2, 0); aa[1] = ldA(ra, 3, 0);
        __builtin_amdgcn_s_barrier();
        asm volatile("s_waitcnt lgkmcnt(0)" ::: "memory");
        __builtin_amdgcn_s_setprio(1);
#pragma unroll
        for (int i = 0; i < 2; i++)
#pragma unroll
            for (int ni = 0; ni < NI; ni++)
                acc[2 + i][ni] = MFMA16(aa[i], bfr[ni], acc[2 + i][ni]);
        __builtin_amdgcn_s_setprio(0);
        __builtin_amdgcn_s_barrier();
        __builtin_amdgcn_sched_barrier(0);

        // ---- phase 2: kk=1, mi 0..1; read B(kk1); stage B(t+2) ----
#pragma unroll
        for (int ni = 0; ni < NI; ni++) bfr[ni] = ldB(rbo, ni, 1);
        aa[0] = ldA(ra, 0, 1); aa[1] = ldA(ra, 1, 1);
        if (pf) stB(t + 2, ps);
        __builtin_amdgcn_s_barrier();
        asm volatile("s_waitcnt lgkmcnt(0)" ::: "memory");
        __builtin_amdgcn_s_setprio(1);
#pragma unroll
        for (int i = 0; i < 2; i++)
#pragma unroll
            for (int ni = 0; ni < NI; ni++)
                acc[i][ni] = MFMA16(aa[i], bfr[ni], acc[i][ni]);
        __builtin_amdgcn_s_setprio(0);
        __builtin_amdgcn_s_barrier();
        __builtin_amdgcn_sched_barrier(0);

        // ---- phase 3: kk=1, mi 2..3; per-tile counted vmcnt ----
        aa[0] = ldA(ra, 2, 1); aa[1] = ldA(ra, 3, 1);
        if (pf) {
            // only tile t+2's INFL loads may remain -> tile t+1 landed
            if constexpr (INFL == 5) asm volatile("s_waitcnt vmcnt(5)" ::: "memory");
            else                     asm volatile("s_waitcnt vmcnt(6)" ::: "memory");
        } else {
            asm volatile("s_waitcnt vmcnt(0)" ::: "memory");
        }
        __builtin_amdgcn_s_barrier();
        asm volatile("s_waitcnt lgkmcnt(0)" ::: "memory");
        __builtin_amdgcn_s_setprio(1);
#pragma unroll
        for (int i = 0; i < 2; i++)
#pragma unroll
            for (int ni = 0; ni < NI; ni++)
                acc[2 + i][ni] = MFMA16(aa[i], bfr[ni], acc[2 + i][ni]);
        __builtin_amdgcn_s_setprio(0);
        __builtin_amdgcn_s_barrier();
        __builtin_amdgcn_sched_barrier(0);

        rs = (rs == 2) ? 0 : rs + 1;
        ps = (ps == 2) ? 0 : ps + 1;
    }

    // epilogue
#pragma unroll
    for (int mi = 0; mi < MI; mi++) {
        int rowb = m0 + wr * (MI * 16) + mi * 16 + quad * 4;
#pragma unroll
        for (int ni = 0; ni < NI; ni++) {
            int col = n0 + wc * (NI * 16) + ni * 16 + row16;
#pragma unroll
            for (int r = 0; r < 4; r++) {
                size_t idx = (size_t)(rowb + r) * N + col;
                float  v   = acc[mi][ni][r];
                if (oF) ((float*)C)[idx] = v;
                else    ((bf16*)C)[idx]  = __float2bfloat16(v);
            }
        }
    }
}

// ---------------------------------------------------------------------------
// RoPE + RMSNorm in place in qkv; q additionally scaled by QSCALE. (unchanged)
__global__ __launch_bounds__(256)
void rope_rms(bf16* __restrict__ qkv, const void* __restrict__ cosp,
              const void* __restrict__ sinp, const int* __restrict__ flagp)
{
    const bool f = *flagp != 0;
    const int wg   = blockIdx.x * 4 + (threadIdx.x >> 6);
    const int lane = threadIdx.x & 63;
    const int s    = wg % 20;
    const int m    = wg / 20;
    const int t    = m & (TSEQ - 1);

    const int col = (s < 16) ? s * HD : CE + (s - 16) * HD;
    bf16* p = qkv + (size_t)m * NQKV + col;

    float xlo = __bfloat162float(p[lane]);
    float xhi = __bfloat162float(p[lane + 64]);
    float cl  = ldf(cosp, t * HD + lane, f);
    float sl  = ldf(sinp, t * HD + lane, f);
    float ch  = ldf(cosp, t * HD + 64 + lane, f);
    float sh  = ldf(sinp, t * HD + 64 + lane, f);

    float rlo = xlo * cl - xhi * sl;
    float rhi = xhi * ch + xlo * sh;

    float ss = rlo * rlo + rhi * rhi;
#pragma unroll
    for (int off = 32; off > 0; off >>= 1)
        ss += __shfl_xor(ss, off, 64);
    float inv = rsqrtf(ss * (1.0f / 128.0f) + 1.1920929e-07f);
    if (s < 16) inv *= QSCALE;

    p[lane]      = __float2bfloat16(rlo * inv);
    p[lane + 64] = __float2bfloat16(rhi * inv);
}

// ---------------------------------------------------------------------------
// vtrans: LDS-tiled transpose (coalesced both sides). (unchanged, verified R7)
__global__ __launch_bounds__(256)
void vtrans(const bf16* __restrict__ qkv, bf16* __restrict__ vt)
{
    __shared__ __bf16 tl[64][136];

    const int tid = threadIdx.x;
    const int bh  = blockIdx.x >> 5;          // 0..7 = b*4+hk
    const int t0  = (blockIdx.x & 31) * 64;
    const int b   = bh >> 2;
    const int hk  = bh & 3;

    const bf16* src = qkv + ((size_t)(b * TSEQ + t0)) * NQKV + 2560 + hk * HD;
#pragma unroll
    for (int it = 0; it < 4; ++it) {
        int idx  = it * 256 + tid;
        int trow = idx >> 4;
        int dcol = (idx & 15) * 8;
        *(uint4*)&tl[trow][dcol] = *(const uint4*)(src + (size_t)trow * NQKV + dcol);
    }
    __syncthreads();

    bf16* dst = vt + ((size_t)(bh * HD)) * TSEQ + t0;
#pragma unroll
    for (int it = 0; it < 4; ++it) {
        int idx  = it * 256 + tid;
        int drow = idx >> 3;
        int tcol = (idx & 7) * 8;
        bf16x8 v;
#pragma unroll
        for (int j = 0; j < 8; ++j)
            v[j] = tl[tcol + j][drow];
        *(bf16x8*)(dst + (size_t)drow * TSEQ + tcol) = v;
    }
}

// ---------------------------------------------------------------------------
// Flash attention (unchanged, verified R7): paired-balanced, Pl XOR-swizzle.
__global__ __launch_bounds__(512, 2)
void attn(bf16* __restrict__ qkv, const bf16* __restrict__ vt)
{
    __shared__ __bf16 Ks[2][64][128];   // swizzled image, 2x16KB
    __shared__ __bf16 Vs[2][128][64];   // swizzled image, 2x16KB
    __shared__ __bf16 Pl[8][16][64];    // per-wave P transpose, XOR-swz, 16KB

    const int tid   = threadIdx.x;
    const int lane  = tid & 63;
    const int wid   = tid >> 6;
    const int row16 = lane & 15;
    const int quad  = lane >> 4;
    const int b   = blockIdx.y >> 2;
    const int hk  = blockIdx.y & 3;
    const int h   = hk * 4 + (wid & 3);   // wave's q-head
    const int mh  = wid >> 2;             // wave's 16-row half of the 32-row tile
    const int p   = blockIdx.x;           // 0..31

    const bf16* Kp = qkv + ((size_t)(b * TSEQ)) * NQKV + CE + hk * HD;
    const bf16* Vp = vt + ((size_t)(b * 4 + hk) * HD) * TSEQ;

    char* const KsB = (char*)Ks;
    char* const VsB = (char*)Vs;
    char* const PlB = (char*)Pl;

    auto stage = [&](int buf, int k0) {
#pragma unroll
        for (int i = 0; i < 2; i++) {
            int kr = (wid << 3) + i * 4 + (lane >> 4);
            int kc = (lane & 15) ^ (kr & 7);
            gld16(Kp + (size_t)(k0 + kr) * NQKV + kc * 8,
                  KsB + buf * 16384 + ((wid << 3) + i * 4) * 256 + lane * 16);
            int vr = (wid << 4) + i * 8 + (lane >> 3);
            int vc = (lane & 7) ^ (vr & 7);
            gld16(Vp + (size_t)vr * TSEQ + k0 + vc * 8,
                  VsB + buf * 16384 + ((wid << 4) + i * 8) * 128 + lane * 16);
        }
    };

    for (int pass = 0; pass < 2; ++pass) {
        const int xi  = pass ? 63 - p : p;     // 32-row q-tile index 0..63
        const int nkt = (xi >> 1) + 1;         // causal k-tiles (64-wide)
        const int qr0 = xi * 32 + mh * 16;     // wave's first q row

        const bf16* Q = qkv + ((size_t)(b * TSEQ + qr0)) * NQKV + h * HD;
        bf16x8 aq[4];
#pragma unroll
        for (int ds = 0; ds < 4; ds++)
            aq[ds] = *(const bf16x8*)(Q + (size_t)row16 * NQKV + ds * 32 + quad * 8);

        f32x4 o[8];
#pragma unroll
        for (int dt = 0; dt < 8; dt++) o[dt] = (f32x4){0.f, 0.f, 0.f, 0.f};
        float lsum[4] = {0.f, 0.f, 0.f, 0.f};

        __syncthreads();          // prior pass's LDS reads complete
        stage(0, 0);
        __syncthreads();          // tile 0 landed

        for (int t = 0; t < nkt; ++t) {
            const int cur = t & 1;
            if (t + 1 < nkt) stage(cur ^ 1, (t + 1) * 64);   // prefetch

            // QK^T: 16 MFMA
            f32x4 s[4];
#pragma unroll
            for (int kg = 0; kg < 4; kg++) s[kg] = (f32x4){0.f, 0.f, 0.f, 0.f};
            __builtin_amdgcn_s_setprio(1);
#pragma unroll
            for (int ds = 0; ds < 4; ds++) {
#pragma unroll
                for (int kg = 0; kg < 4; kg++) {
                    int krow = kg * 16 + row16;
                    int phys = (ds * 4 + quad) ^ (row16 & 7);
                    bf16x8 kf = *(const bf16x8*)(KsB + cur * 16384 + krow * 256 + phys * 16);
                    s[kg] = MFMA16(aq[ds], kf, s[kg]);
                }
            }
            __builtin_amdgcn_s_setprio(0);

            const bool diag = (t == nkt - 1);
            const int  k0   = t * 64;
            const int  r16h = row16 >> 3;
            const int  r16l = (row16 & 7) * 2;
#pragma unroll
            for (int r = 0; r < 4; r++) {
                float pv[4];
                int prow = quad * 4 + r;
                int qrow = qr0 + prow;
#pragma unroll
                for (int kg = 0; kg < 4; kg++) {
                    float e = __builtin_amdgcn_exp2f(s[kg][r] - M2);
                    pv[kg] = (!diag || (k0 + kg * 16 + row16 <= qrow)) ? e : 0.f;
                }
                lsum[r] += (pv[0] + pv[1]) + (pv[2] + pv[3]);
#pragma unroll
                for (int kg = 0; kg < 4; kg++)
                    *(__bf16*)(PlB + wid * 2048 + prow * 128
                               + (((kg * 2 + r16h) ^ (prow & 7)) << 4) + r16l)
                        = (__bf16)pv[kg];
            }
            __asm__ volatile("" ::: "memory");

            // PV: 16 MFMA
            __builtin_amdgcn_s_setprio(1);
#pragma unroll
            for (int c = 0; c < 2; c++) {
                bf16x8 pf = *(const bf16x8*)(PlB + wid * 2048 + row16 * 128
                                             + ((((c << 2) + quad) ^ (row16 & 7)) << 4));
#pragma unroll
                for (int dt = 0; dt < 8; dt++) {
                    int vrow = dt * 16 + row16;
                    int phys = (c * 4 + quad) ^ (row16 & 7);
                    bf16x8 vf = *(const bf16x8*)(VsB + cur * 16384 + vrow * 128 + phys * 16);
                    o[dt] = MFMA16(pf, vf, o[dt]);
                }
            }
            __builtin_amdgcn_s_setprio(0);
            __asm__ volatile("" ::: "memory");
            __syncthreads();   // reads of `cur` done; prefetch landed
        }

        // final 16-lane reduction of l per row; write O into qkv's Q slot
#pragma unroll
        for (int r = 0; r < 4; r++) {
            float l = lsum[r];
#pragma unroll
            for (int off = 1; off < 16; off <<= 1)
                l += __shfl_xor(l, off, 64);
            float rl = 1.0f / l;
            int trow = qr0 + quad * 4 + r;
            bf16* dst = qkv + ((size_t)(b * TSEQ + trow)) * NQKV + h * HD;
#pragma unroll
            for (int dt = 0; dt < 8; dt++)
                dst[dt * 16 + row16] = __float2bfloat16(o[dt][r] * rl);
        }
    }
}

// ---------------------------------------------------------------------------
extern "C" void kernel_launch(void* const* d_in, const int* in_sizes, int n_in,
                              void* d_out, int out_size, void* d_ws, size_t ws_size,
                              hipStream_t stream)
{
    // ws (bf16 elems): qkv [4096,3072] 25.2MB | vt 4.2MB | wqkvb [3072,2048]
    // 12.6MB (reused for wprojb after gemm1) | flag | xb [4096,2048] 16.8MB.
    bf16* qkv   = (bf16*)d_ws;
    bf16* vt    = qkv + (size_t)BT * NQKV;
    bf16* wqkvb = vt + (size_t)2 * 4 * HD * TSEQ;
    int* flagp  = (int*)(wqkvb + (size_t)NQKV * CE);
    bf16* xb    = wqkvb + (size_t)NQKV * CE + 16;   // 32B after flag, 16B-aligned

    const size_t need = ((size_t)BT * NQKV + (size_t)2 * 4 * HD * TSEQ
                         + (size_t)NQKV * CE + 16 + (size_t)BT * CE) * sizeof(bf16);
    const bool useXb = ws_size >= need;

    // 0) detect input dtype -> device flag
    detect_dtype<<<1, 256, 0, stream>>>((const unsigned short*)d_in[0], flagp);

    // 1) convert wq/wk/wv to fused bf16 [3072][2048]
    conv_bf16<<<(2048 * 2048 / 8) / 256, 256, 0, stream>>>(d_in[3], wqkvb, flagp);
    conv_bf16<<<(512 * 2048 / 8) / 256, 256, 0, stream>>>(d_in[4], wqkvb + (size_t)2048 * 2048, flagp);
    conv_bf16<<<(512 * 2048 / 8) / 256, 256, 0, stream>>>(d_in[5], wqkvb + (size_t)2560 * 2048, flagp);

    // 2) fused QKV projection: BN=192 -> 16x32 = 512 blocks (2 clean rounds)
    if (useXb) {
        conv_bf16<<<(BT * CE / 8) / 256, 256, 0, stream>>>(d_in[0], xb, flagp);
        gemmQ<4, 3><<<dim3(NQKV / 192, BT / 128), 512, 0, stream>>>(
            xb, wqkvb, qkv, BT, NQKV, CE, CE, 0, flagp);
    } else {
        gemm_bt<<<dim3(NQKV / 128, BT / 128), 256, 0, stream>>>(
            d_in[0], wqkvb, qkv, BT, NQKV, CE, CE, 1, 0, flagp);
    }

    // 3) convert wproj into the same buffer (stream-ordered after gemm1)
    conv_bf16<<<(2048 * 2048 / 8) / 256, 256, 0, stream>>>(d_in[6], wqkvb, flagp);

    // 4) V transpose to [B,KV,D,T] (LDS-tiled, coalesced both sides)
    vtrans<<<256, 256, 0, stream>>>(qkv, vt);

    // 5) RoPE + RMSNorm in place (q scaled by QSCALE)
    rope_rms<<<(BT * 20) / 4, 256, 0, stream>>>(qkv, d_in[1], d_in[2], flagp);

    // 6) balanced GQA-fused flash attention; O overwrites qkv's Q columns
    attn<<<dim3(32, 2 * 4), 512, 0, stream>>>(qkv, vt);

    // 7) output projection: BN=256 -> 8x32 = 256 blocks (full fill)
    if (useXb) {
        gemmQ<4, 4><<<dim3(CE / 256, BT / 128), 512, 0, stream>>>(
            qkv, wqkvb, d_out, BT, CE, CE, NQKV, 1, flagp);
    } else {
        gemm_bt<<<dim3(CE / 128, BT / 128), 256, 0, stream>>>(
            qkv, wqkvb, d_out, BT, CE, CE, NQKV, 0, 1, flagp);
    }
}

// Round 10
// 307.445 us; speedup vs baseline: 1.1175x; 1.1175x over previous
//
#include <hip/hip_runtime.h>
#include <hip/hip_bf16.h>

typedef __hip_bfloat16 bf16;
typedef __attribute__((ext_vector_type(8))) __bf16 bf16x8;
typedef __attribute__((ext_vector_type(4))) float f32x4;

#define MFMA16(a, b, c) __builtin_amdgcn_mfma_f32_16x16x32_bf16((a), (b), (c), 0, 0, 0)

#define BT 4096      // B*T rows
#define CE 2048      // embed dim
#define NQKV 3072    // q(2048) + k(512) + v(512)
#define TSEQ 2048
#define HD 128

// q pre-scale: 1/sqrt(128) * log2(e), folded into rope_rms's q output.
#define QSCALE (0.08838834764831845f * 1.4426950408889634f)
// fixed softmax max bound: ||q'||*||k|| = 128*QSCALE (Cauchy-Schwarz on
// RMS-normalized vectors). p = 2^(s' - M2) <= ~1, no online max needed.
#define M2 16.3222f

// ---------------------------------------------------------------------------
// async global->LDS 16B copy (one instruction, no VGPR round trip)
__device__ __forceinline__ void gld16(const void* g, void* l)
{
    __builtin_amdgcn_global_load_lds(
        (const __attribute__((address_space(1))) void*)g,
        (__attribute__((address_space(3))) void*)l, 16, 0, 0);
}

// ---------------------------------------------------------------------------
// Input-dtype detector (inputs are fp32; gate kept for safety).
__global__ void detect_dtype(const unsigned short* __restrict__ x, int* __restrict__ flag)
{
    __shared__ int cnt;
    if (threadIdx.x == 0) cnt = 0;
    __syncthreads();
    unsigned short w = x[2 * threadIdx.x];
    int e = (w >> 7) & 0xFF;
    atomicAdd(&cnt, (e >= 117 && e <= 130) ? 1 : 0);
    __syncthreads();
    if (threadIdx.x == 0) *flag = (cnt < 128) ? 1 : 0;
}

// Stage 8 elems (16B bf16) into LDS from bf16 or fp32 source (VGPR convert).
__device__ __forceinline__ void stage8(short* dst, const void* src, size_t eoff, bool f32)
{
    if (f32) {
        const float* s = (const float*)src + eoff;
        float4 f0 = *(const float4*)s;
        float4 f1 = *(const float4*)(s + 4);
        bf16x8 v;
        v[0] = (__bf16)f0.x; v[1] = (__bf16)f0.y; v[2] = (__bf16)f0.z; v[3] = (__bf16)f0.w;
        v[4] = (__bf16)f1.x; v[5] = (__bf16)f1.y; v[6] = (__bf16)f1.z; v[7] = (__bf16)f1.w;
        *(bf16x8*)dst = v;
    } else {
        *(uint4*)dst = *(const uint4*)((const bf16*)src + eoff);
    }
}

__device__ __forceinline__ float ldf(const void* p, int i, bool f32)
{
    return f32 ? ((const float*)p)[i] : __bfloat162float(((const bf16*)p)[i]);
}

// ---------------------------------------------------------------------------
// fp32 (or bf16) -> bf16 conversion, 8 elems/thread.
__global__ __launch_bounds__(256)
void conv_bf16(const void* __restrict__ src, bf16* __restrict__ dst,
               const int* __restrict__ flagp)
{
    const bool f = *flagp != 0;
    size_t i8 = (size_t)blockIdx.x * 256 + threadIdx.x;
    stage8((short*)(dst + i8 * 8), src, i8 * 8, f);
}

// ---------------------------------------------------------------------------
// Legacy 128^2 GEMM, kept ONLY as ws-constrained fallback (fp32-A staging).
__global__ __launch_bounds__(256)
void gemm_bt(const void* __restrict__ A, const bf16* __restrict__ W,
             void* __restrict__ C, int M, int N, int K, int lda,
             int aGate, int oGate, const int* __restrict__ flagp)
{
    __shared__ short As[128][32];
    __shared__ short Bs[128][32];

    const int f = *flagp;
    const bool aF = aGate && f, oF = oGate && f;

    const int tid   = threadIdx.x;
    const int lane  = tid & 63;
    const int wid   = tid >> 6;
    const int row16 = lane & 15;
    const int quad  = lane >> 4;
    const int wr    = wid >> 1;
    const int wc    = wid & 1;
    const int m0    = blockIdx.y * 128;
    const int n0    = blockIdx.x * 128;

    const int rl4 = wid * 16 + (lane >> 2);
    const int c8  = (lane & 3) * 8;

    f32x4 acc[4][4];
#pragma unroll
    for (int i = 0; i < 4; i++)
#pragma unroll
        for (int j = 0; j < 4; j++)
            acc[i][j] = (f32x4){0.f, 0.f, 0.f, 0.f};

    for (int k0 = 0; k0 < K; k0 += 32) {
#pragma unroll
        for (int i = 0; i < 2; i++) {
            int r = i * 64 + rl4;
            gld16(W + (size_t)(n0 + r) * K + k0 + c8, &Bs[r][c8]);
        }
        if (!aF) {
#pragma unroll
            for (int i = 0; i < 2; i++) {
                int r = i * 64 + rl4;
                gld16((const bf16*)A + (size_t)(m0 + r) * lda + k0 + c8, &As[r][c8]);
            }
        } else {
#pragma unroll
            for (int i = 0; i < 2; i++) {
                int c = i * 256 + tid;
                int row = c >> 2, col = (c & 3) << 3;
                stage8(&As[row][col], A, (size_t)(m0 + row) * lda + k0 + col, true);
            }
        }
        __syncthreads();

        bf16x8 af[4], bfv[4];
#pragma unroll
        for (int mi = 0; mi < 4; mi++)
            af[mi] = *(const bf16x8*)&As[wr * 64 + mi * 16 + row16][quad * 8];
#pragma unroll
        for (int ni = 0; ni < 4; ni++)
            bfv[ni] = *(const bf16x8*)&Bs[wc * 64 + ni * 16 + row16][quad * 8];
#pragma unroll
        for (int mi = 0; mi < 4; mi++)
#pragma unroll
            for (int ni = 0; ni < 4; ni++)
                acc[mi][ni] = MFMA16(af[mi], bfv[ni], acc[mi][ni]);
        __syncthreads();
    }

#pragma unroll
    for (int mi = 0; mi < 4; mi++) {
        int rowb = m0 + wr * 64 + mi * 16 + quad * 4;
#pragma unroll
        for (int ni = 0; ni < 4; ni++) {
            int col = n0 + wc * 64 + ni * 16 + row16;
#pragma unroll
            for (int r = 0; r < 4; r++) {
                size_t idx = (size_t)(rowb + r) * N + col;
                float  v   = acc[mi][ni][r];
                if (oF) ((float*)C)[idx] = v;
                else    ((bf16*)C)[idx]  = __float2bfloat16(v);
            }
        }
    }
}

// ---------------------------------------------------------------------------
// gemmP (R7-verified, 321us build; gemmQ's 4-phase split REVERTED -- it
// regressed 72->88us: 6-8 MFMA per phase can't cover 2 barriers+lgkmcnt;
// single vmcnt(0)+barrier per 64-K window wins at this tile size).
// BM=MI*32 x BN=256, BK=64, 512 thr / 8 waves, double-buffered LDS,
// full-row XOR swizzle via pre-swizzled global source, bijective XCD swizzle.
template<int MI>
__global__ __launch_bounds__(512, 2)
void gemmP(const bf16* __restrict__ A, const bf16* __restrict__ W,
           void* __restrict__ C, int M, int N, int K, int lda,
           int oGate, const int* __restrict__ flagp)
{
    constexpr int BM     = MI * 32;
    constexpr int ABYTES = BM * 128;        // bytes per A K-tile (BK=64 bf16)
    constexpr int AUL    = ABYTES / 8192;   // gld16 per thread for A (4 or 2)

    __shared__ __bf16 As[2][BM][64];
    __shared__ __bf16 Bs[2][256][64];

    const bool oF = oGate && (*flagp != 0);

    // XCD swizzle: hardware slot lin -> logical tile swz (bijective, nwg%8==0)
    const int gx  = gridDim.x;
    const int lin = blockIdx.y * gx + blockIdx.x;
    const int cpx = (gx * gridDim.y) >> 3;
    const int swzid = (lin & 7) * cpx + (lin >> 3);
    const int bx = swzid % gx;
    const int by = swzid / gx;

    const int tid   = threadIdx.x;
    const int lane  = tid & 63;
    const int wid   = tid >> 6;
    const int row16 = lane & 15;
    const int quad  = lane >> 4;
    const int wr    = wid >> 2;          // 0..1
    const int wc    = wid & 3;           // 0..3
    const int m0    = by * BM;
    const int n0    = bx * 256;
    const int NT    = K >> 6;            // 64-wide K-tiles

    const int srow = tid >> 3;                        // 0..63
    const int sc8  = ((tid & 7) ^ (srow & 7)) * 8;    // element offset
    const bf16* Ag = A + (size_t)(m0 + srow) * lda + sc8;
    const bf16* Bg = W + (size_t)(n0 + srow) * K   + sc8;
    char* const AsB = (char*)As;
    char* const BsB = (char*)Bs;
    const int sdst = tid * 16;

    auto stA = [&](int kt, int b) {
#pragma unroll
        for (int u = 0; u < AUL; ++u)
            gld16(Ag + (size_t)(u * 64) * lda + kt * 64,
                  AsB + b * ABYTES + u * 8192 + sdst);
    };
    auto stB = [&](int kt, int b) {
#pragma unroll
        for (int u = 0; u < 4; ++u)
            gld16(Bg + (size_t)(u * 64) * K + kt * 64,
                  BsB + b * 32768 + u * 8192 + sdst);
    };

    const int swz  = ((quad ^ (row16 & 7)) * 16);          // kk=0
    const int swz1 = (((4 + quad) ^ (row16 & 7)) * 16);    // kk=1
    const int aRow = wr * (MI * 16) + row16;
    const int bRow = wc * 64 + row16;

    auto ldA = [&](int b, int mi, int kk) -> bf16x8 {
        return *(const bf16x8*)(AsB + b * ABYTES + (aRow + mi * 16) * 128
                                + (kk ? swz1 : swz));
    };
    auto ldB = [&](int b, int ni, int kk) -> bf16x8 {
        return *(const bf16x8*)(BsB + b * 32768 + (bRow + ni * 16) * 128
                                + (kk ? swz1 : swz));
    };

    f32x4 acc[MI][4];
#pragma unroll
    for (int i = 0; i < MI; i++)
#pragma unroll
        for (int j = 0; j < 4; j++)
            acc[i][j] = (f32x4){0.f, 0.f, 0.f, 0.f};

    stA(0, 0); stB(0, 0);
    asm volatile("s_waitcnt vmcnt(0)" ::: "memory");
    __builtin_amdgcn_s_barrier();
    __builtin_amdgcn_sched_barrier(0);

    for (int t = 0; t < NT; ++t) {
        const int rb = t & 1;
        const int wb = rb ^ 1;

        bf16x8 bfr[4][2];
#pragma unroll
        for (int ni = 0; ni < 4; ni++)
#pragma unroll
            for (int kk = 0; kk < 2; kk++)
                bfr[ni][kk] = ldB(rb, ni, kk);
        bf16x8 a0[2][2];
#pragma unroll
        for (int i = 0; i < 2; i++)
#pragma unroll
            for (int kk = 0; kk < 2; kk++)
                a0[i][kk] = ldA(rb, i, kk);

        if (t + 1 < NT) { stB(t + 1, wb); stA(t + 1, wb); }

        __builtin_amdgcn_s_setprio(1);
#pragma unroll
        for (int kk = 0; kk < 2; kk++)
#pragma unroll
            for (int i = 0; i < 2; i++)
#pragma unroll
                for (int ni = 0; ni < 4; ni++)
                    acc[i][ni] = MFMA16(a0[i][kk], bfr[ni][kk], acc[i][ni]);
        __builtin_amdgcn_s_setprio(0);

#pragma unroll
        for (int p = 1; p < MI / 2; ++p) {
            bf16x8 ap[2][2];
#pragma unroll
            for (int i = 0; i < 2; i++)
#pragma unroll
                for (int kk = 0; kk < 2; kk++)
                    ap[i][kk] = ldA(rb, 2 * p + i, kk);
            __builtin_amdgcn_s_setprio(1);
#pragma unroll
            for (int kk = 0; kk < 2; kk++)
#pragma unroll
                for (int i = 0; i < 2; i++)
#pragma unroll
                    for (int ni = 0; ni < 4; ni++)
                        acc[2 * p + i][ni] =
                            MFMA16(ap[i][kk], bfr[ni][kk], acc[2 * p + i][ni]);
            __builtin_amdgcn_s_setprio(0);
        }

        asm volatile("s_waitcnt vmcnt(0)" ::: "memory");
        __builtin_amdgcn_s_barrier();
        __builtin_amdgcn_sched_barrier(0);
    }

#pragma unroll
    for (int mi = 0; mi < MI; mi++) {
        int rowb = m0 + wr * (MI * 16) + mi * 16 + quad * 4;
#pragma unroll
        for (int ni = 0; ni < 4; ni++) {
            int col = n0 + wc * 64 + ni * 16 + row16;
#pragma unroll
            for (int r = 0; r < 4; r++) {
                size_t idx = (size_t)(rowb + r) * N + col;
                float  v   = acc[mi][ni][r];
                if (oF) ((float*)C)[idx] = v;
                else    ((bf16*)C)[idx]  = __float2bfloat16(v);
            }
        }
    }
}

// ---------------------------------------------------------------------------
// RoPE + RMSNorm in place in qkv; q additionally scaled by QSCALE. (unchanged)
__global__ __launch_bounds__(256)
void rope_rms(bf16* __restrict__ qkv, const void* __restrict__ cosp,
              const void* __restrict__ sinp, const int* __restrict__ flagp)
{
    const bool f = *flagp != 0;
    const int wg   = blockIdx.x * 4 + (threadIdx.x >> 6);
    const int lane = threadIdx.x & 63;
    const int s    = wg % 20;
    const int m    = wg / 20;
    const int t    = m & (TSEQ - 1);

    const int col = (s < 16) ? s * HD : CE + (s - 16) * HD;
    bf16* p = qkv + (size_t)m * NQKV + col;

    float xlo = __bfloat162float(p[lane]);
    float xhi = __bfloat162float(p[lane + 64]);
    float cl  = ldf(cosp, t * HD + lane, f);
    float sl  = ldf(sinp, t * HD + lane, f);
    float ch  = ldf(cosp, t * HD + 64 + lane, f);
    float sh  = ldf(sinp, t * HD + 64 + lane, f);

    float rlo = xlo * cl - xhi * sl;
    float rhi = xhi * ch + xlo * sh;

    float ss = rlo * rlo + rhi * rhi;
#pragma unroll
    for (int off = 32; off > 0; off >>= 1)
        ss += __shfl_xor(ss, off, 64);
    float inv = rsqrtf(ss * (1.0f / 128.0f) + 1.1920929e-07f);
    if (s < 16) inv *= QSCALE;

    p[lane]      = __float2bfloat16(rlo * inv);
    p[lane + 64] = __float2bfloat16(rhi * inv);
}

// ---------------------------------------------------------------------------
// vtrans: LDS-tiled transpose (coalesced both sides). (unchanged, verified R7)
__global__ __launch_bounds__(256)
void vtrans(const bf16* __restrict__ qkv, bf16* __restrict__ vt)
{
    __shared__ __bf16 tl[64][136];

    const int tid = threadIdx.x;
    const int bh  = blockIdx.x >> 5;          // 0..7 = b*4+hk
    const int t0  = (blockIdx.x & 31) * 64;
    const int b   = bh >> 2;
    const int hk  = bh & 3;

    const bf16* src = qkv + ((size_t)(b * TSEQ + t0)) * NQKV + 2560 + hk * HD;
#pragma unroll
    for (int it = 0; it < 4; ++it) {
        int idx  = it * 256 + tid;
        int trow = idx >> 4;
        int dcol = (idx & 15) * 8;
        *(uint4*)&tl[trow][dcol] = *(const uint4*)(src + (size_t)trow * NQKV + dcol);
    }
    __syncthreads();

    bf16* dst = vt + ((size_t)(bh * HD)) * TSEQ + t0;
#pragma unroll
    for (int it = 0; it < 4; ++it) {
        int idx  = it * 256 + tid;
        int drow = idx >> 3;
        int tcol = (idx & 7) * 8;
        bf16x8 v;
#pragma unroll
        for (int j = 0; j < 8; ++j)
            v[j] = tl[tcol + j][drow];
        *(bf16x8*)(dst + (size_t)drow * TSEQ + tcol) = v;
    }
}

// ---------------------------------------------------------------------------
// Flash attention R10: 2-heads/wave + key-split (halves LDS read traffic).
// R7 counters: DS-pipe-bound (272 b128 reads/block-iter; each wave re-reads
// the full K,V tiles for 1 MFMA per read). New wave decomposition:
//   wave (hp, mh, ks) = (head-pair, 16-row half, 32-key half):
//   each kf/vf read feeds TWO MFMAs (both heads of the pair), and each wave
//   touches only its 32-key half -> 144 reads/block-iter, same 256 MFMA.
// o and lsum become partial over keys: pass-end exchange through the
// then-dead Ks/Vs region (ks=1 waves store, ks=0 waves add + write O).
// Grid/pairing/LDS/staging identical to the verified R7 kernel.
__global__ __launch_bounds__(512, 2)
void attn(bf16* __restrict__ qkv, const bf16* __restrict__ vt)
{
    __shared__ char lds[81920];
    char* const KsB = lds;             // 2 x 16KB K tiles (swizzled image)
    char* const VsB = lds + 32768;     // 2 x 16KB V tiles (swizzled image)
    char* const PlB = lds + 65536;     // 16KB: per-wave P [wid][h2][16][32]

    const int tid   = threadIdx.x;
    const int lane  = tid & 63;
    const int wid   = tid >> 6;
    const int row16 = lane & 15;
    const int quad  = lane >> 4;
    const int b   = blockIdx.y >> 2;
    const int hk  = blockIdx.y & 3;
    const int hp  = wid & 1;              // head-pair within hk group
    const int mh  = (wid >> 1) & 1;       // 16-row half of the 32-row tile
    const int ks  = wid >> 2;             // 32-key half
    const int h0  = hk * 4 + hp * 2;      // first of the wave's two heads
    const int p   = blockIdx.x;           // 0..31

    const bf16* Kp = qkv + ((size_t)(b * TSEQ)) * NQKV + CE + hk * HD;
    const bf16* Vp = vt + ((size_t)(b * 4 + hk) * HD) * TSEQ;

    // staging (unchanged): wave w owns K rows [8w,8w+8), V rows [16w,16w+16);
    // linear LDS dest, swizzle via pre-swizzled per-lane GLOBAL address.
    auto stage = [&](int buf, int k0) {
#pragma unroll
        for (int i = 0; i < 2; i++) {
            int kr = (wid << 3) + i * 4 + (lane >> 4);
            int kc = (lane & 15) ^ (kr & 7);
            gld16(Kp + (size_t)(k0 + kr) * NQKV + kc * 8,
                  KsB + buf * 16384 + ((wid << 3) + i * 4) * 256 + lane * 16);
            int vr = (wid << 4) + i * 8 + (lane >> 3);
            int vc = (lane & 7) ^ (vr & 7);
            gld16(Vp + (size_t)vr * TSEQ + k0 + vc * 8,
                  VsB + buf * 16384 + ((wid << 4) + i * 8) * 128 + lane * 16);
        }
    };

    for (int pass = 0; pass < 2; ++pass) {
        const int xi  = pass ? 63 - p : p;     // 32-row q-tile index 0..63
        const int nkt = (xi >> 1) + 1;         // causal k-tiles (64-wide)
        const int qr0 = xi * 32 + mh * 16;     // wave's first q row

        const bf16* Q = qkv + ((size_t)(b * TSEQ + qr0)) * NQKV + h0 * HD;
        bf16x8 aq[2][4];
#pragma unroll
        for (int h2 = 0; h2 < 2; h2++)
#pragma unroll
            for (int ds = 0; ds < 4; ds++)
                aq[h2][ds] = *(const bf16x8*)(Q + h2 * HD
                             + (size_t)row16 * NQKV + ds * 32 + quad * 8);

        f32x4 o[2][8];
#pragma unroll
        for (int h2 = 0; h2 < 2; h2++)
#pragma unroll
            for (int dt = 0; dt < 8; dt++)
                o[h2][dt] = (f32x4){0.f, 0.f, 0.f, 0.f};
        f32x4 lsum[2] = {(f32x4){0.f,0.f,0.f,0.f}, (f32x4){0.f,0.f,0.f,0.f}};

        __syncthreads();          // prior pass's scratch reads complete
        stage(0, 0);
        __syncthreads();          // tile 0 landed

        for (int t = 0; t < nkt; ++t) {
            const int cur = t & 1;
            if (t + 1 < nkt) stage(cur ^ 1, (t + 1) * 64);   // prefetch

            // QK^T: 8 kf reads feed 16 MFMA (2 heads)
            f32x4 s[2][2];
#pragma unroll
            for (int h2 = 0; h2 < 2; h2++)
#pragma unroll
                for (int kgl = 0; kgl < 2; kgl++)
                    s[h2][kgl] = (f32x4){0.f, 0.f, 0.f, 0.f};
            __builtin_amdgcn_s_setprio(1);
#pragma unroll
            for (int ds = 0; ds < 4; ds++) {
#pragma unroll
                for (int kgl = 0; kgl < 2; kgl++) {
                    int krow = (ks * 2 + kgl) * 16 + row16;
                    int phys = (ds * 4 + quad) ^ (krow & 7);
                    bf16x8 kf = *(const bf16x8*)(KsB + cur * 16384
                                                 + krow * 256 + phys * 16);
                    s[0][kgl] = MFMA16(aq[0][ds], kf, s[0][kgl]);
                    s[1][kgl] = MFMA16(aq[1][ds], kf, s[1][kgl]);
                }
            }
            __builtin_amdgcn_s_setprio(0);

            // fixed-max softmax numerators (this wave's 32 keys); P -> LDS.
            // Pl per wave: [wid][h2] 16 rows x 32 keys (64B rows, XOR swz
            // phys4 = chunk ^ (row&3)).
            const bool diag = (t == nkt - 1);
            const int  kbase = t * 64 + ks * 32;
            const int  r16h = row16 >> 3;
            const int  r16l = (row16 & 7) * 2;
#pragma unroll
            for (int h2 = 0; h2 < 2; h2++) {
#pragma unroll
                for (int r = 0; r < 4; r++) {
                    int prow = quad * 4 + r;
                    int qrow = qr0 + prow;
                    float pv0, pv1;
                    {
                        float e0 = __builtin_amdgcn_exp2f(s[h2][0][r] - M2);
                        float e1 = __builtin_amdgcn_exp2f(s[h2][1][r] - M2);
                        pv0 = (!diag || (kbase + row16      <= qrow)) ? e0 : 0.f;
                        pv1 = (!diag || (kbase + 16 + row16 <= qrow)) ? e1 : 0.f;
                    }
                    lsum[h2][r] += pv0 + pv1;
                    char* base = PlB + wid * 2048 + h2 * 1024 + prow * 64;
                    *(__bf16*)(base + (((0 * 2 + r16h) ^ (prow & 3)) << 4) + r16l)
                        = (__bf16)pv0;
                    *(__bf16*)(base + (((1 * 2 + r16h) ^ (prow & 3)) << 4) + r16l)
                        = (__bf16)pv1;
                }
            }
            __asm__ volatile("" ::: "memory");

            // PV (this wave's key half): 2 pf + 8 vf reads feed 16 MFMA
            __builtin_amdgcn_s_setprio(1);
            bf16x8 pf0 = *(const bf16x8*)(PlB + wid * 2048 + row16 * 64
                                          + ((quad ^ (row16 & 3)) << 4));
            bf16x8 pf1 = *(const bf16x8*)(PlB + wid * 2048 + 1024 + row16 * 64
                                          + ((quad ^ (row16 & 3)) << 4));
#pragma unroll
            for (int dt = 0; dt < 8; dt++) {
                int vrow = dt * 16 + row16;
                int phys = (ks * 4 + quad) ^ (vrow & 7);
                bf16x8 vf = *(const bf16x8*)(VsB + cur * 16384
                                             + vrow * 128 + phys * 16);
                o[0][dt] = MFMA16(pf0, vf, o[0][dt]);
                o[1][dt] = MFMA16(pf1, vf, o[1][dt]);
            }
            __builtin_amdgcn_s_setprio(0);
            __asm__ volatile("" ::: "memory");
            __syncthreads();   // reads of `cur` done; prefetch landed
        }

        // ---- pass-end: combine ks halves, then write O ----
        const int g = (hp << 1) | mh;         // 0..3
        char* const scr = lds + g * 16384;    // 16KB per group in Ks/Vs region
        __syncthreads();                      // K/V tiles dead; scratch safe
        if (ks) {
#pragma unroll
            for (int h2 = 0; h2 < 2; h2++)
#pragma unroll
                for (int dt = 0; dt < 8; dt++)
                    *(f32x4*)(scr + (h2 * 8 + dt) * 1024 + lane * 16) = o[h2][dt];
            *(f32x4*)(PlB + g * 4096 + lane * 32)      = lsum[0];
            *(f32x4*)(PlB + g * 4096 + lane * 32 + 16) = lsum[1];
        }
        __syncthreads();
        if (!ks) {
#pragma unroll
            for (int h2 = 0; h2 < 2; h2++)
#pragma unroll
                for (int dt = 0; dt < 8; dt++)
                    o[h2][dt] += *(const f32x4*)(scr + (h2 * 8 + dt) * 1024
                                                 + lane * 16);
            f32x4 l0 = *(const f32x4*)(PlB + g * 4096 + lane * 32);
            f32x4 l1 = *(const f32x4*)(PlB + g * 4096 + lane * 32 + 16);
#pragma unroll
            for (int h2 = 0; h2 < 2; h2++) {
#pragma unroll
                for (int r = 0; r < 4; r++) {
                    float l = lsum[h2][r] + (h2 ? l1[r] : l0[r]);
#pragma unroll
                    for (int off = 1; off < 16; off <<= 1)
                        l += __shfl_xor(l, off, 64);
                    float rl = 1.0f / l;
                    int trow = qr0 + quad * 4 + r;
                    bf16* dst = qkv + ((size_t)(b * TSEQ + trow)) * NQKV
                                + (h0 + h2) * HD;
#pragma unroll
                    for (int dt = 0; dt < 8; dt++)
                        dst[dt * 16 + row16] = __float2bfloat16(o[h2][dt][r] * rl);
                }
            }
        }
    }
}

// ---------------------------------------------------------------------------
extern "C" void kernel_launch(void* const* d_in, const int* in_sizes, int n_in,
                              void* d_out, int out_size, void* d_ws, size_t ws_size,
                              hipStream_t stream)
{
    // ws (bf16 elems): qkv [4096,3072] 25.2MB | vt 4.2MB | wqkvb [3072,2048]
    // 12.6MB (reused for wprojb after gemm1) | flag | xb [4096,2048] 16.8MB.
    bf16* qkv   = (bf16*)d_ws;
    bf16* vt    = qkv + (size_t)BT * NQKV;
    bf16* wqkvb = vt + (size_t)2 * 4 * HD * TSEQ;
    int* flagp  = (int*)(wqkvb + (size_t)NQKV * CE);
    bf16* xb    = wqkvb + (size_t)NQKV * CE + 16;   // 32B after flag, 16B-aligned

    const size_t need = ((size_t)BT * NQKV + (size_t)2 * 4 * HD * TSEQ
                         + (size_t)NQKV * CE + 16 + (size_t)BT * CE) * sizeof(bf16);
    const bool useXb = ws_size >= need;

    // 0) detect input dtype -> device flag
    detect_dtype<<<1, 256, 0, stream>>>((const unsigned short*)d_in[0], flagp);

    // 1) convert wq/wk/wv to fused bf16 [3072][2048]
    conv_bf16<<<(2048 * 2048 / 8) / 256, 256, 0, stream>>>(d_in[3], wqkvb, flagp);
    conv_bf16<<<(512 * 2048 / 8) / 256, 256, 0, stream>>>(d_in[4], wqkvb + (size_t)2048 * 2048, flagp);
    conv_bf16<<<(512 * 2048 / 8) / 256, 256, 0, stream>>>(d_in[5], wqkvb + (size_t)2560 * 2048, flagp);

    // 2) fused QKV projection
    if (useXb) {
        conv_bf16<<<(BT * CE / 8) / 256, 256, 0, stream>>>(d_in[0], xb, flagp);
        gemmP<8><<<dim3(NQKV / 256, BT / 256), 512, 0, stream>>>(
            xb, wqkvb, qkv, BT, NQKV, CE, CE, 0, flagp);
    } else {
        gemm_bt<<<dim3(NQKV / 128, BT / 128), 256, 0, stream>>>(
            d_in[0], wqkvb, qkv, BT, NQKV, CE, CE, 1, 0, flagp);
    }

    // 3) convert wproj into the same buffer (stream-ordered after gemm1)
    conv_bf16<<<(2048 * 2048 / 8) / 256, 256, 0, stream>>>(d_in[6], wqkvb, flagp);

    // 4) V transpose to [B,KV,D,T] (LDS-tiled, coalesced both sides)
    vtrans<<<256, 256, 0, stream>>>(qkv, vt);

    // 5) RoPE + RMSNorm in place (q scaled by QSCALE)
    rope_rms<<<(BT * 20) / 4, 256, 0, stream>>>(qkv, d_in[1], d_in[2], flagp);

    // 6) balanced GQA-fused flash attention; O overwrites qkv's Q columns
    attn<<<dim3(32, 2 * 4), 512, 0, stream>>>(qkv, vt);

    // 7) output projection: A=qkv cols 0..2047 (bf16, lda=3072)
    if (useXb) {
        gemmP<4><<<dim3(CE / 256, BT / 128), 512, 0, stream>>>(
            qkv, wqkvb, d_out, BT, CE, CE, NQKV, 1, flagp);
    } else {
        gemm_bt<<<dim3(CE / 128, BT / 128), 256, 0, stream>>>(
            qkv, wqkvb, d_out, BT, CE, CE, NQKV, 0, 1, flagp);
    }
}

// Round 11
// 304.165 us; speedup vs baseline: 1.1295x; 1.0108x over previous
//
#include <hip/hip_runtime.h>
#include <hip/hip_bf16.h>

typedef __hip_bfloat16 bf16;
typedef __attribute__((ext_vector_type(8))) __bf16 bf16x8;
typedef __attribute__((ext_vector_type(4))) float f32x4;

#define MFMA16(a, b, c) __builtin_amdgcn_mfma_f32_16x16x32_bf16((a), (b), (c), 0, 0, 0)

#define BT 4096      // B*T rows
#define CE 2048      // embed dim
#define NQKV 3072    // q(2048) + k(512) + v(512)
#define TSEQ 2048
#define HD 128

// q pre-scale: 1/sqrt(128) * log2(e), folded into rope_rms's q output.
#define QSCALE (0.08838834764831845f * 1.4426950408889634f)
// fixed softmax max bound: ||q'||*||k|| = 128*QSCALE (Cauchy-Schwarz on
// RMS-normalized vectors). p = 2^(s' - M2) <= ~1, no online max needed.
#define M2 16.3222f

// ---------------------------------------------------------------------------
// async global->LDS 16B copy (one instruction, no VGPR round trip)
__device__ __forceinline__ void gld16(const void* g, void* l)
{
    __builtin_amdgcn_global_load_lds(
        (const __attribute__((address_space(1))) void*)g,
        (__attribute__((address_space(3))) void*)l, 16, 0, 0);
}

// ---------------------------------------------------------------------------
// Input-dtype detector (inputs are fp32; gate kept for safety).
__global__ void detect_dtype(const unsigned short* __restrict__ x, int* __restrict__ flag)
{
    __shared__ int cnt;
    if (threadIdx.x == 0) cnt = 0;
    __syncthreads();
    unsigned short w = x[2 * threadIdx.x];
    int e = (w >> 7) & 0xFF;
    atomicAdd(&cnt, (e >= 117 && e <= 130) ? 1 : 0);
    __syncthreads();
    if (threadIdx.x == 0) *flag = (cnt < 128) ? 1 : 0;
}

// Stage 8 elems (16B bf16) into LDS from bf16 or fp32 source (VGPR convert).
__device__ __forceinline__ void stage8(short* dst, const void* src, size_t eoff, bool f32)
{
    if (f32) {
        const float* s = (const float*)src + eoff;
        float4 f0 = *(const float4*)s;
        float4 f1 = *(const float4*)(s + 4);
        bf16x8 v;
        v[0] = (__bf16)f0.x; v[1] = (__bf16)f0.y; v[2] = (__bf16)f0.z; v[3] = (__bf16)f0.w;
        v[4] = (__bf16)f1.x; v[5] = (__bf16)f1.y; v[6] = (__bf16)f1.z; v[7] = (__bf16)f1.w;
        *(bf16x8*)dst = v;
    } else {
        *(uint4*)dst = *(const uint4*)((const bf16*)src + eoff);
    }
}

__device__ __forceinline__ float ldf(const void* p, int i, bool f32)
{
    return f32 ? ((const float*)p)[i] : __bfloat162float(((const bf16*)p)[i]);
}

// ---------------------------------------------------------------------------
// fp32 (or bf16) -> bf16 conversion, 8 elems/thread.
__global__ __launch_bounds__(256)
void conv_bf16(const void* __restrict__ src, bf16* __restrict__ dst,
               const int* __restrict__ flagp)
{
    const bool f = *flagp != 0;
    size_t i8 = (size_t)blockIdx.x * 256 + threadIdx.x;
    stage8((short*)(dst + i8 * 8), src, i8 * 8, f);
}

// ---------------------------------------------------------------------------
// Legacy 128^2 GEMM, kept ONLY as ws-constrained fallback (fp32-A staging).
__global__ __launch_bounds__(256)
void gemm_bt(const void* __restrict__ A, const bf16* __restrict__ W,
             void* __restrict__ C, int M, int N, int K, int lda,
             int aGate, int oGate, const int* __restrict__ flagp)
{
    __shared__ short As[128][32];
    __shared__ short Bs[128][32];

    const int f = *flagp;
    const bool aF = aGate && f, oF = oGate && f;

    const int tid   = threadIdx.x;
    const int lane  = tid & 63;
    const int wid   = tid >> 6;
    const int row16 = lane & 15;
    const int quad  = lane >> 4;
    const int wr    = wid >> 1;
    const int wc    = wid & 1;
    const int m0    = blockIdx.y * 128;
    const int n0    = blockIdx.x * 128;

    const int rl4 = wid * 16 + (lane >> 2);
    const int c8  = (lane & 3) * 8;

    f32x4 acc[4][4];
#pragma unroll
    for (int i = 0; i < 4; i++)
#pragma unroll
        for (int j = 0; j < 4; j++)
            acc[i][j] = (f32x4){0.f, 0.f, 0.f, 0.f};

    for (int k0 = 0; k0 < K; k0 += 32) {
#pragma unroll
        for (int i = 0; i < 2; i++) {
            int r = i * 64 + rl4;
            gld16(W + (size_t)(n0 + r) * K + k0 + c8, &Bs[r][c8]);
        }
        if (!aF) {
#pragma unroll
            for (int i = 0; i < 2; i++) {
                int r = i * 64 + rl4;
                gld16((const bf16*)A + (size_t)(m0 + r) * lda + k0 + c8, &As[r][c8]);
            }
        } else {
#pragma unroll
            for (int i = 0; i < 2; i++) {
                int c = i * 256 + tid;
                int row = c >> 2, col = (c & 3) << 3;
                stage8(&As[row][col], A, (size_t)(m0 + row) * lda + k0 + col, true);
            }
        }
        __syncthreads();

        bf16x8 af[4], bfv[4];
#pragma unroll
        for (int mi = 0; mi < 4; mi++)
            af[mi] = *(const bf16x8*)&As[wr * 64 + mi * 16 + row16][quad * 8];
#pragma unroll
        for (int ni = 0; ni < 4; ni++)
            bfv[ni] = *(const bf16x8*)&Bs[wc * 64 + ni * 16 + row16][quad * 8];
#pragma unroll
        for (int mi = 0; mi < 4; mi++)
#pragma unroll
            for (int ni = 0; ni < 4; ni++)
                acc[mi][ni] = MFMA16(af[mi], bfv[ni], acc[mi][ni]);
        __syncthreads();
    }

#pragma unroll
    for (int mi = 0; mi < 4; mi++) {
        int rowb = m0 + wr * 64 + mi * 16 + quad * 4;
#pragma unroll
        for (int ni = 0; ni < 4; ni++) {
            int col = n0 + wc * 64 + ni * 16 + row16;
#pragma unroll
            for (int r = 0; r < 4; r++) {
                size_t idx = (size_t)(rowb + r) * N + col;
                float  v   = acc[mi][ni][r];
                if (oF) ((float*)C)[idx] = v;
                else    ((bf16*)C)[idx]  = __float2bfloat16(v);
            }
        }
    }
}

// ---------------------------------------------------------------------------
// gemmP<MI, NIW> (R7/R10-verified schedule, now N-generalized for grid fill):
// BM=MI*32 x BN=NIW*64, BK=64, 512 thr / 8 waves (2M x 4N; per-wave
// MI/2*32 rows x NIW*16 cols), double-buffered LDS, ONE vmcnt(0)+barrier per
// 64-K window (gemmQ's thin 4-phase split REVERTED in R10 -- it regressed
// 72->88us), full-row XOR swizzle via pre-swizzled global source, bijective
// XCD swizzle (total blocks % 8 == 0 required).
//   gemm1: <8,3> BM=256,BN=192 -> grid 16x16 = 256 blocks = FULL fill
//          (was <8,4> at 192 blocks = 75% fill, Occupancy 14.9%). LDS 112KB.
//   gemm2: <4,4> BM=128,BN=256 -> grid  8x32 = 256 blocks (unchanged).
template<int MI, int NIW>
__global__ __launch_bounds__(512, 2)
void gemmP(const bf16* __restrict__ A, const bf16* __restrict__ W,
           void* __restrict__ C, int M, int N, int K, int lda,
           int oGate, const int* __restrict__ flagp)
{
    constexpr int BM     = MI * 32;
    constexpr int BN     = NIW * 64;
    constexpr int ABYTES = BM * 128;        // bytes per A K-tile (BK=64 bf16)
    constexpr int BBYTES = BN * 128;        // bytes per B K-tile
    constexpr int AUL    = BM / 64;         // gld16 per thread for A
    constexpr int BUL    = BN / 64;         // gld16 per thread for B

    __shared__ __bf16 As[2][BM][64];
    __shared__ __bf16 Bs[2][BN][64];

    const bool oF = oGate && (*flagp != 0);

    // XCD swizzle: hardware slot lin -> logical tile swz (bijective, nwg%8==0)
    const int gx  = gridDim.x;
    const int lin = blockIdx.y * gx + blockIdx.x;
    const int cpx = (gx * gridDim.y) >> 3;
    const int swzid = (lin & 7) * cpx + (lin >> 3);
    const int bx = swzid % gx;
    const int by = swzid / gx;

    const int tid   = threadIdx.x;
    const int lane  = tid & 63;
    const int wid   = tid >> 6;
    const int row16 = lane & 15;
    const int quad  = lane >> 4;
    const int wr    = wid >> 2;          // 0..1
    const int wc    = wid & 3;           // 0..3
    const int m0    = by * BM;
    const int n0    = bx * BN;
    const int NT    = K >> 6;            // 64-wide K-tiles

    const int srow = tid >> 3;                        // 0..63
    const int sc8  = ((tid & 7) ^ (srow & 7)) * 8;    // element offset
    const bf16* Ag = A + (size_t)(m0 + srow) * lda + sc8;
    const bf16* Bg = W + (size_t)(n0 + srow) * K   + sc8;
    char* const AsB = (char*)As;
    char* const BsB = (char*)Bs;
    const int sdst = tid * 16;

    auto stA = [&](int kt, int b) {
#pragma unroll
        for (int u = 0; u < AUL; ++u)
            gld16(Ag + (size_t)(u * 64) * lda + kt * 64,
                  AsB + b * ABYTES + u * 8192 + sdst);
    };
    auto stB = [&](int kt, int b) {
#pragma unroll
        for (int u = 0; u < BUL; ++u)
            gld16(Bg + (size_t)(u * 64) * K + kt * 64,
                  BsB + b * BBYTES + u * 8192 + sdst);
    };

    const int swz  = ((quad ^ (row16 & 7)) * 16);          // kk=0
    const int swz1 = (((4 + quad) ^ (row16 & 7)) * 16);    // kk=1
    const int aRow = wr * (MI * 16) + row16;
    const int bRow = wc * (NIW * 16) + row16;

    auto ldA = [&](int b, int mi, int kk) -> bf16x8 {
        return *(const bf16x8*)(AsB + b * ABYTES + (aRow + mi * 16) * 128
                                + (kk ? swz1 : swz));
    };
    auto ldB = [&](int b, int ni, int kk) -> bf16x8 {
        return *(const bf16x8*)(BsB + b * BBYTES + (bRow + ni * 16) * 128
                                + (kk ? swz1 : swz));
    };

    f32x4 acc[MI][NIW];
#pragma unroll
    for (int i = 0; i < MI; i++)
#pragma unroll
        for (int j = 0; j < NIW; j++)
            acc[i][j] = (f32x4){0.f, 0.f, 0.f, 0.f};

    stA(0, 0); stB(0, 0);
    asm volatile("s_waitcnt vmcnt(0)" ::: "memory");
    __builtin_amdgcn_s_barrier();
    __builtin_amdgcn_sched_barrier(0);

    for (int t = 0; t < NT; ++t) {
        const int rb = t & 1;
        const int wb = rb ^ 1;

        bf16x8 bfr[NIW][2];
#pragma unroll
        for (int ni = 0; ni < NIW; ni++)
#pragma unroll
            for (int kk = 0; kk < 2; kk++)
                bfr[ni][kk] = ldB(rb, ni, kk);
        bf16x8 a0[2][2];
#pragma unroll
        for (int i = 0; i < 2; i++)
#pragma unroll
            for (int kk = 0; kk < 2; kk++)
                a0[i][kk] = ldA(rb, i, kk);

        if (t + 1 < NT) { stB(t + 1, wb); stA(t + 1, wb); }

        __builtin_amdgcn_s_setprio(1);
#pragma unroll
        for (int kk = 0; kk < 2; kk++)
#pragma unroll
            for (int i = 0; i < 2; i++)
#pragma unroll
                for (int ni = 0; ni < NIW; ni++)
                    acc[i][ni] = MFMA16(a0[i][kk], bfr[ni][kk], acc[i][ni]);
        __builtin_amdgcn_s_setprio(0);

#pragma unroll
        for (int p = 1; p < MI / 2; ++p) {
            bf16x8 ap[2][2];
#pragma unroll
            for (int i = 0; i < 2; i++)
#pragma unroll
                for (int kk = 0; kk < 2; kk++)
                    ap[i][kk] = ldA(rb, 2 * p + i, kk);
            __builtin_amdgcn_s_setprio(1);
#pragma unroll
            for (int kk = 0; kk < 2; kk++)
#pragma unroll
                for (int i = 0; i < 2; i++)
#pragma unroll
                    for (int ni = 0; ni < NIW; ni++)
                        acc[2 * p + i][ni] =
                            MFMA16(ap[i][kk], bfr[ni][kk], acc[2 * p + i][ni]);
            __builtin_amdgcn_s_setprio(0);
        }

        asm volatile("s_waitcnt vmcnt(0)" ::: "memory");
        __builtin_amdgcn_s_barrier();
        __builtin_amdgcn_sched_barrier(0);
    }

#pragma unroll
    for (int mi = 0; mi < MI; mi++) {
        int rowb = m0 + wr * (MI * 16) + mi * 16 + quad * 4;
#pragma unroll
        for (int ni = 0; ni < NIW; ni++) {
            int col = n0 + wc * (NIW * 16) + ni * 16 + row16;
#pragma unroll
            for (int r = 0; r < 4; r++) {
                size_t idx = (size_t)(rowb + r) * N + col;
                float  v   = acc[mi][ni][r];
                if (oF) ((float*)C)[idx] = v;
                else    ((bf16*)C)[idx]  = __float2bfloat16(v);
            }
        }
    }
}

// ---------------------------------------------------------------------------
// RoPE + RMSNorm in place in qkv; q additionally scaled by QSCALE. (unchanged)
__global__ __launch_bounds__(256)
void rope_rms(bf16* __restrict__ qkv, const void* __restrict__ cosp,
              const void* __restrict__ sinp, const int* __restrict__ flagp)
{
    const bool f = *flagp != 0;
    const int wg   = blockIdx.x * 4 + (threadIdx.x >> 6);
    const int lane = threadIdx.x & 63;
    const int s    = wg % 20;
    const int m    = wg / 20;
    const int t    = m & (TSEQ - 1);

    const int col = (s < 16) ? s * HD : CE + (s - 16) * HD;
    bf16* p = qkv + (size_t)m * NQKV + col;

    float xlo = __bfloat162float(p[lane]);
    float xhi = __bfloat162float(p[lane + 64]);
    float cl  = ldf(cosp, t * HD + lane, f);
    float sl  = ldf(sinp, t * HD + lane, f);
    float ch  = ldf(cosp, t * HD + 64 + lane, f);
    float sh  = ldf(sinp, t * HD + 64 + lane, f);

    float rlo = xlo * cl - xhi * sl;
    float rhi = xhi * ch + xlo * sh;

    float ss = rlo * rlo + rhi * rhi;
#pragma unroll
    for (int off = 32; off > 0; off >>= 1)
        ss += __shfl_xor(ss, off, 64);
    float inv = rsqrtf(ss * (1.0f / 128.0f) + 1.1920929e-07f);
    if (s < 16) inv *= QSCALE;

    p[lane]      = __float2bfloat16(rlo * inv);
    p[lane + 64] = __float2bfloat16(rhi * inv);
}

// ---------------------------------------------------------------------------
// vtrans: LDS-tiled transpose (coalesced both sides). (unchanged, verified R7)
__global__ __launch_bounds__(256)
void vtrans(const bf16* __restrict__ qkv, bf16* __restrict__ vt)
{
    __shared__ __bf16 tl[64][136];

    const int tid = threadIdx.x;
    const int bh  = blockIdx.x >> 5;          // 0..7 = b*4+hk
    const int t0  = (blockIdx.x & 31) * 64;
    const int b   = bh >> 2;
    const int hk  = bh & 3;

    const bf16* src = qkv + ((size_t)(b * TSEQ + t0)) * NQKV + 2560 + hk * HD;
#pragma unroll
    for (int it = 0; it < 4; ++it) {
        int idx  = it * 256 + tid;
        int trow = idx >> 4;
        int dcol = (idx & 15) * 8;
        *(uint4*)&tl[trow][dcol] = *(const uint4*)(src + (size_t)trow * NQKV + dcol);
    }
    __syncthreads();

    bf16* dst = vt + ((size_t)(bh * HD)) * TSEQ + t0;
#pragma unroll
    for (int it = 0; it < 4; ++it) {
        int idx  = it * 256 + tid;
        int drow = idx >> 3;
        int tcol = (idx & 7) * 8;
        bf16x8 v;
#pragma unroll
        for (int j = 0; j < 8; ++j)
            v[j] = tl[tcol + j][drow];
        *(bf16x8*)(dst + (size_t)drow * TSEQ + tcol) = v;
    }
}

// ---------------------------------------------------------------------------
// Flash attention (unchanged, verified R10): 2-heads/wave + key-split.
__global__ __launch_bounds__(512, 2)
void attn(bf16* __restrict__ qkv, const bf16* __restrict__ vt)
{
    __shared__ char lds[81920];
    char* const KsB = lds;             // 2 x 16KB K tiles (swizzled image)
    char* const VsB = lds + 32768;     // 2 x 16KB V tiles (swizzled image)
    char* const PlB = lds + 65536;     // 16KB: per-wave P [wid][h2][16][32]

    const int tid   = threadIdx.x;
    const int lane  = tid & 63;
    const int wid   = tid >> 6;
    const int row16 = lane & 15;
    const int quad  = lane >> 4;
    const int b   = blockIdx.y >> 2;
    const int hk  = blockIdx.y & 3;
    const int hp  = wid & 1;              // head-pair within hk group
    const int mh  = (wid >> 1) & 1;       // 16-row half of the 32-row tile
    const int ks  = wid >> 2;             // 32-key half
    const int h0  = hk * 4 + hp * 2;      // first of the wave's two heads
    const int p   = blockIdx.x;           // 0..31

    const bf16* Kp = qkv + ((size_t)(b * TSEQ)) * NQKV + CE + hk * HD;
    const bf16* Vp = vt + ((size_t)(b * 4 + hk) * HD) * TSEQ;

    auto stage = [&](int buf, int k0) {
#pragma unroll
        for (int i = 0; i < 2; i++) {
            int kr = (wid << 3) + i * 4 + (lane >> 4);
            int kc = (lane & 15) ^ (kr & 7);
            gld16(Kp + (size_t)(k0 + kr) * NQKV + kc * 8,
                  KsB + buf * 16384 + ((wid << 3) + i * 4) * 256 + lane * 16);
            int vr = (wid << 4) + i * 8 + (lane >> 3);
            int vc = (lane & 7) ^ (vr & 7);
            gld16(Vp + (size_t)vr * TSEQ + k0 + vc * 8,
                  VsB + buf * 16384 + ((wid << 4) + i * 8) * 128 + lane * 16);
        }
    };

    for (int pass = 0; pass < 2; ++pass) {
        const int xi  = pass ? 63 - p : p;     // 32-row q-tile index 0..63
        const int nkt = (xi >> 1) + 1;         // causal k-tiles (64-wide)
        const int qr0 = xi * 32 + mh * 16;     // wave's first q row

        const bf16* Q = qkv + ((size_t)(b * TSEQ + qr0)) * NQKV + h0 * HD;
        bf16x8 aq[2][4];
#pragma unroll
        for (int h2 = 0; h2 < 2; h2++)
#pragma unroll
            for (int ds = 0; ds < 4; ds++)
                aq[h2][ds] = *(const bf16x8*)(Q + h2 * HD
                             + (size_t)row16 * NQKV + ds * 32 + quad * 8);

        f32x4 o[2][8];
#pragma unroll
        for (int h2 = 0; h2 < 2; h2++)
#pragma unroll
            for (int dt = 0; dt < 8; dt++)
                o[h2][dt] = (f32x4){0.f, 0.f, 0.f, 0.f};
        f32x4 lsum[2] = {(f32x4){0.f,0.f,0.f,0.f}, (f32x4){0.f,0.f,0.f,0.f}};

        __syncthreads();          // prior pass's scratch reads complete
        stage(0, 0);
        __syncthreads();          // tile 0 landed

        for (int t = 0; t < nkt; ++t) {
            const int cur = t & 1;
            if (t + 1 < nkt) stage(cur ^ 1, (t + 1) * 64);   // prefetch

            // QK^T: 8 kf reads feed 16 MFMA (2 heads)
            f32x4 s[2][2];
#pragma unroll
            for (int h2 = 0; h2 < 2; h2++)
#pragma unroll
                for (int kgl = 0; kgl < 2; kgl++)
                    s[h2][kgl] = (f32x4){0.f, 0.f, 0.f, 0.f};
            __builtin_amdgcn_s_setprio(1);
#pragma unroll
            for (int ds = 0; ds < 4; ds++) {
#pragma unroll
                for (int kgl = 0; kgl < 2; kgl++) {
                    int krow = (ks * 2 + kgl) * 16 + row16;
                    int phys = (ds * 4 + quad) ^ (krow & 7);
                    bf16x8 kf = *(const bf16x8*)(KsB + cur * 16384
                                                 + krow * 256 + phys * 16);
                    s[0][kgl] = MFMA16(aq[0][ds], kf, s[0][kgl]);
                    s[1][kgl] = MFMA16(aq[1][ds], kf, s[1][kgl]);
                }
            }
            __builtin_amdgcn_s_setprio(0);

            const bool diag = (t == nkt - 1);
            const int  kbase = t * 64 + ks * 32;
            const int  r16h = row16 >> 3;
            const int  r16l = (row16 & 7) * 2;
#pragma unroll
            for (int h2 = 0; h2 < 2; h2++) {
#pragma unroll
                for (int r = 0; r < 4; r++) {
                    int prow = quad * 4 + r;
                    int qrow = qr0 + prow;
                    float pv0, pv1;
                    {
                        float e0 = __builtin_amdgcn_exp2f(s[h2][0][r] - M2);
                        float e1 = __builtin_amdgcn_exp2f(s[h2][1][r] - M2);
                        pv0 = (!diag || (kbase + row16      <= qrow)) ? e0 : 0.f;
                        pv1 = (!diag || (kbase + 16 + row16 <= qrow)) ? e1 : 0.f;
                    }
                    lsum[h2][r] += pv0 + pv1;
                    char* base = PlB + wid * 2048 + h2 * 1024 + prow * 64;
                    *(__bf16*)(base + (((0 * 2 + r16h) ^ (prow & 3)) << 4) + r16l)
                        = (__bf16)pv0;
                    *(__bf16*)(base + (((1 * 2 + r16h) ^ (prow & 3)) << 4) + r16l)
                        = (__bf16)pv1;
                }
            }
            __asm__ volatile("" ::: "memory");

            // PV (this wave's key half): 2 pf + 8 vf reads feed 16 MFMA
            __builtin_amdgcn_s_setprio(1);
            bf16x8 pf0 = *(const bf16x8*)(PlB + wid * 2048 + row16 * 64
                                          + ((quad ^ (row16 & 3)) << 4));
            bf16x8 pf1 = *(const bf16x8*)(PlB + wid * 2048 + 1024 + row16 * 64
                                          + ((quad ^ (row16 & 3)) << 4));
#pragma unroll
            for (int dt = 0; dt < 8; dt++) {
                int vrow = dt * 16 + row16;
                int phys = (ks * 4 + quad) ^ (vrow & 7);
                bf16x8 vf = *(const bf16x8*)(VsB + cur * 16384
                                             + vrow * 128 + phys * 16);
                o[0][dt] = MFMA16(pf0, vf, o[0][dt]);
                o[1][dt] = MFMA16(pf1, vf, o[1][dt]);
            }
            __builtin_amdgcn_s_setprio(0);
            __asm__ volatile("" ::: "memory");
            __syncthreads();   // reads of `cur` done; prefetch landed
        }

        // ---- pass-end: combine ks halves, then write O ----
        const int g = (hp << 1) | mh;         // 0..3
        char* const scr = lds + g * 16384;    // 16KB per group in Ks/Vs region
        __syncthreads();                      // K/V tiles dead; scratch safe
        if (ks) {
#pragma unroll
            for (int h2 = 0; h2 < 2; h2++)
#pragma unroll
                for (int dt = 0; dt < 8; dt++)
                    *(f32x4*)(scr + (h2 * 8 + dt) * 1024 + lane * 16) = o[h2][dt];
            *(f32x4*)(PlB + g * 4096 + lane * 32)      = lsum[0];
            *(f32x4*)(PlB + g * 4096 + lane * 32 + 16) = lsum[1];
        }
        __syncthreads();
        if (!ks) {
#pragma unroll
            for (int h2 = 0; h2 < 2; h2++)
#pragma unroll
                for (int dt = 0; dt < 8; dt++)
                    o[h2][dt] += *(const f32x4*)(scr + (h2 * 8 + dt) * 1024
                                                 + lane * 16);
            f32x4 l0 = *(const f32x4*)(PlB + g * 4096 + lane * 32);
            f32x4 l1 = *(const f32x4*)(PlB + g * 4096 + lane * 32 + 16);
#pragma unroll
            for (int h2 = 0; h2 < 2; h2++) {
#pragma unroll
                for (int r = 0; r < 4; r++) {
                    float l = lsum[h2][r] + (h2 ? l1[r] : l0[r]);
#pragma unroll
                    for (int off = 1; off < 16; off <<= 1)
                        l += __shfl_xor(l, off, 64);
                    float rl = 1.0f / l;
                    int trow = qr0 + quad * 4 + r;
                    bf16* dst = qkv + ((size_t)(b * TSEQ + trow)) * NQKV
                                + (h0 + h2) * HD;
#pragma unroll
                    for (int dt = 0; dt < 8; dt++)
                        dst[dt * 16 + row16] = __float2bfloat16(o[h2][dt][r] * rl);
                }
            }
        }
    }
}

// ---------------------------------------------------------------------------
extern "C" void kernel_launch(void* const* d_in, const int* in_sizes, int n_in,
                              void* d_out, int out_size, void* d_ws, size_t ws_size,
                              hipStream_t stream)
{
    // ws (bf16 elems): qkv [4096,3072] 25.2MB | vt 4.2MB | wqkvb [3072,2048]
    // 12.6MB (reused for wprojb after gemm1) | flag | xb [4096,2048] 16.8MB.
    bf16* qkv   = (bf16*)d_ws;
    bf16* vt    = qkv + (size_t)BT * NQKV;
    bf16* wqkvb = vt + (size_t)2 * 4 * HD * TSEQ;
    int* flagp  = (int*)(wqkvb + (size_t)NQKV * CE);
    bf16* xb    = wqkvb + (size_t)NQKV * CE + 16;   // 32B after flag, 16B-aligned

    const size_t need = ((size_t)BT * NQKV + (size_t)2 * 4 * HD * TSEQ
                         + (size_t)NQKV * CE + 16 + (size_t)BT * CE) * sizeof(bf16);
    const bool useXb = ws_size >= need;

    // 0) detect input dtype -> device flag
    detect_dtype<<<1, 256, 0, stream>>>((const unsigned short*)d_in[0], flagp);

    // 1) convert wq/wk/wv to fused bf16 [3072][2048]
    conv_bf16<<<(2048 * 2048 / 8) / 256, 256, 0, stream>>>(d_in[3], wqkvb, flagp);
    conv_bf16<<<(512 * 2048 / 8) / 256, 256, 0, stream>>>(d_in[4], wqkvb + (size_t)2048 * 2048, flagp);
    conv_bf16<<<(512 * 2048 / 8) / 256, 256, 0, stream>>>(d_in[5], wqkvb + (size_t)2560 * 2048, flagp);

    // 2) fused QKV projection: BM=256 x BN=192 -> 16x16 = 256 blocks (FULL fill)
    if (useXb) {
        conv_bf16<<<(BT * CE / 8) / 256, 256, 0, stream>>>(d_in[0], xb, flagp);
        gemmP<8, 3><<<dim3(NQKV / 192, BT / 256), 512, 0, stream>>>(
            xb, wqkvb, qkv, BT, NQKV, CE, CE, 0, flagp);
    } else {
        gemm_bt<<<dim3(NQKV / 128, BT / 128), 256, 0, stream>>>(
            d_in[0], wqkvb, qkv, BT, NQKV, CE, CE, 1, 0, flagp);
    }

    // 3) convert wproj into the same buffer (stream-ordered after gemm1)
    conv_bf16<<<(2048 * 2048 / 8) / 256, 256, 0, stream>>>(d_in[6], wqkvb, flagp);

    // 4) V transpose to [B,KV,D,T] (LDS-tiled, coalesced both sides)
    vtrans<<<256, 256, 0, stream>>>(qkv, vt);

    // 5) RoPE + RMSNorm in place (q scaled by QSCALE)
    rope_rms<<<(BT * 20) / 4, 256, 0, stream>>>(qkv, d_in[1], d_in[2], flagp);

    // 6) balanced GQA-fused flash attention; O overwrites qkv's Q columns
    attn<<<dim3(32, 2 * 4), 512, 0, stream>>>(qkv, vt);

    // 7) output projection: BM=128 x BN=256 -> 8x32 = 256 blocks (full fill)
    if (useXb) {
        gemmP<4, 4><<<dim3(CE / 256, BT / 128), 512, 0, stream>>>(
            qkv, wqkvb, d_out, BT, CE, CE, NQKV, 1, flagp);
    } else {
        gemm_bt<<<dim3(CE / 128, BT / 128), 256, 0, stream>>>(
            qkv, wqkvb, d_out, BT, CE, CE, NQKV, 0, 1, flagp);
    }
}

// Round 12
// 298.904 us; speedup vs baseline: 1.1494x; 1.0176x over previous
//
#include <hip/hip_runtime.h>
#include <hip/hip_bf16.h>

typedef __hip_bfloat16 bf16;
typedef __attribute__((ext_vector_type(8))) __bf16 bf16x8;
typedef __attribute__((ext_vector_type(4))) float f32x4;

#define MFMA16(a, b, c) __builtin_amdgcn_mfma_f32_16x16x32_bf16((a), (b), (c), 0, 0, 0)

#define BT 4096      // B*T rows
#define CE 2048      // embed dim
#define NQKV 3072    // q(2048) + k(512) + v(512)
#define TSEQ 2048
#define HD 128

// q pre-scale: 1/sqrt(128) * log2(e), folded into rope_rms's q output.
#define QSCALE (0.08838834764831845f * 1.4426950408889634f)
// fixed softmax max bound: ||q'||*||k|| = 128*QSCALE (Cauchy-Schwarz on
// RMS-normalized vectors). p = 2^(s' - M2) <= ~1, no online max needed.
#define M2 16.3222f

// ---------------------------------------------------------------------------
// async global->LDS 16B copy (one instruction, no VGPR round trip)
__device__ __forceinline__ void gld16(const void* g, void* l)
{
    __builtin_amdgcn_global_load_lds(
        (const __attribute__((address_space(1))) void*)g,
        (__attribute__((address_space(3))) void*)l, 16, 0, 0);
}

// ---------------------------------------------------------------------------
// Input-dtype detector (inputs are fp32; gate kept for safety).
__global__ void detect_dtype(const unsigned short* __restrict__ x, int* __restrict__ flag)
{
    __shared__ int cnt;
    if (threadIdx.x == 0) cnt = 0;
    __syncthreads();
    unsigned short w = x[2 * threadIdx.x];
    int e = (w >> 7) & 0xFF;
    atomicAdd(&cnt, (e >= 117 && e <= 130) ? 1 : 0);
    __syncthreads();
    if (threadIdx.x == 0) *flag = (cnt < 128) ? 1 : 0;
}

// Stage 8 elems (16B bf16) into LDS from bf16 or fp32 source (VGPR convert).
__device__ __forceinline__ void stage8(short* dst, const void* src, size_t eoff, bool f32)
{
    if (f32) {
        const float* s = (const float*)src + eoff;
        float4 f0 = *(const float4*)s;
        float4 f1 = *(const float4*)(s + 4);
        bf16x8 v;
        v[0] = (__bf16)f0.x; v[1] = (__bf16)f0.y; v[2] = (__bf16)f0.z; v[3] = (__bf16)f0.w;
        v[4] = (__bf16)f1.x; v[5] = (__bf16)f1.y; v[6] = (__bf16)f1.z; v[7] = (__bf16)f1.w;
        *(bf16x8*)dst = v;
    } else {
        *(uint4*)dst = *(const uint4*)((const bf16*)src + eoff);
    }
}

__device__ __forceinline__ float ldf(const void* p, int i, bool f32)
{
    return f32 ? ((const float*)p)[i] : __bfloat162float(((const bf16*)p)[i]);
}

// ---------------------------------------------------------------------------
// fp32 (or bf16) -> bf16 conversion, 8 elems/thread (single-source; wproj).
__global__ __launch_bounds__(256)
void conv_bf16(const void* __restrict__ src, bf16* __restrict__ dst,
               const int* __restrict__ flagp)
{
    const bool f = *flagp != 0;
    size_t i8 = (size_t)blockIdx.x * 256 + threadIdx.x;
    stage8((short*)(dst + i8 * 8), src, i8 * 8, f);
}

// ---------------------------------------------------------------------------
// R12: fused wq/wk/wv(/x) converter — one launch instead of four. Block-range
// split on i8 (groups of 8 elems): wq [0,524288) | wk [.,655360) |
// wv [.,786432) | x [.,1835008) (x part only launched when useXb).
__global__ __launch_bounds__(256)
void conv_all(const void* __restrict__ wq, const void* __restrict__ wk,
              const void* __restrict__ wv, const void* __restrict__ x,
              bf16* __restrict__ wqkvb, bf16* __restrict__ xb,
              const int* __restrict__ flagp)
{
    const bool f = *flagp != 0;
    size_t i8 = (size_t)blockIdx.x * 256 + threadIdx.x;
    if (i8 < 524288) {
        stage8((short*)(wqkvb + i8 * 8), wq, i8 * 8, f);
    } else if (i8 < 655360) {
        stage8((short*)(wqkvb + i8 * 8), wk, (i8 - 524288) * 8, f);
    } else if (i8 < 786432) {
        stage8((short*)(wqkvb + i8 * 8), wv, (i8 - 655360) * 8, f);
    } else {
        stage8((short*)(xb + (i8 - 786432) * 8), x, (i8 - 786432) * 8, f);
    }
}

// ---------------------------------------------------------------------------
// Legacy 128^2 GEMM, kept ONLY as ws-constrained fallback (fp32-A staging).
__global__ __launch_bounds__(256)
void gemm_bt(const void* __restrict__ A, const bf16* __restrict__ W,
             void* __restrict__ C, int M, int N, int K, int lda,
             int aGate, int oGate, const int* __restrict__ flagp)
{
    __shared__ short As[128][32];
    __shared__ short Bs[128][32];

    const int f = *flagp;
    const bool aF = aGate && f, oF = oGate && f;

    const int tid   = threadIdx.x;
    const int lane  = tid & 63;
    const int wid   = tid >> 6;
    const int row16 = lane & 15;
    const int quad  = lane >> 4;
    const int wr    = wid >> 1;
    const int wc    = wid & 1;
    const int m0    = blockIdx.y * 128;
    const int n0    = blockIdx.x * 128;

    const int rl4 = wid * 16 + (lane >> 2);
    const int c8  = (lane & 3) * 8;

    f32x4 acc[4][4];
#pragma unroll
    for (int i = 0; i < 4; i++)
#pragma unroll
        for (int j = 0; j < 4; j++)
            acc[i][j] = (f32x4){0.f, 0.f, 0.f, 0.f};

    for (int k0 = 0; k0 < K; k0 += 32) {
#pragma unroll
        for (int i = 0; i < 2; i++) {
            int r = i * 64 + rl4;
            gld16(W + (size_t)(n0 + r) * K + k0 + c8, &Bs[r][c8]);
        }
        if (!aF) {
#pragma unroll
            for (int i = 0; i < 2; i++) {
                int r = i * 64 + rl4;
                gld16((const bf16*)A + (size_t)(m0 + r) * lda + k0 + c8, &As[r][c8]);
            }
        } else {
#pragma unroll
            for (int i = 0; i < 2; i++) {
                int c = i * 256 + tid;
                int row = c >> 2, col = (c & 3) << 3;
                stage8(&As[row][col], A, (size_t)(m0 + row) * lda + k0 + col, true);
            }
        }
        __syncthreads();

        bf16x8 af[4], bfv[4];
#pragma unroll
        for (int mi = 0; mi < 4; mi++)
            af[mi] = *(const bf16x8*)&As[wr * 64 + mi * 16 + row16][quad * 8];
#pragma unroll
        for (int ni = 0; ni < 4; ni++)
            bfv[ni] = *(const bf16x8*)&Bs[wc * 64 + ni * 16 + row16][quad * 8];
#pragma unroll
        for (int mi = 0; mi < 4; mi++)
#pragma unroll
            for (int ni = 0; ni < 4; ni++)
                acc[mi][ni] = MFMA16(af[mi], bfv[ni], acc[mi][ni]);
        __syncthreads();
    }

#pragma unroll
    for (int mi = 0; mi < 4; mi++) {
        int rowb = m0 + wr * 64 + mi * 16 + quad * 4;
#pragma unroll
        for (int ni = 0; ni < 4; ni++) {
            int col = n0 + wc * 64 + ni * 16 + row16;
#pragma unroll
            for (int r = 0; r < 4; r++) {
                size_t idx = (size_t)(rowb + r) * N + col;
                float  v   = acc[mi][ni][r];
                if (oF) ((float*)C)[idx] = v;
                else    ((bf16*)C)[idx]  = __float2bfloat16(v);
            }
        }
    }
}

// ---------------------------------------------------------------------------
// R12 gemmS<MI,NIW> = gemmP body (verified) + COUNTED end-of-tile vmcnt via
// mixed buffering. A: 2 slots (staged at top of tile t for t+1, 1 tile of
// latency cover -- unchanged). B: 3 slots, staged TWO tiles ahead.
// Drain proof: end of tile t has in-flight A(t+1)[AUL] + B(t+2)[BUL]
// (B(t+1) drained at end of t-1); vmcnt(BUL) leaves exactly B(t+2) =>
// A(t+1) and B(t+1) proven landed for all waves before the barrier.
// Slot races: B(t+2) -> slot (t+2)%3, last read by tile t-1 (= (t+2)%3),
// synced at end-of-(t-1) barrier < issue point. A(t+1) -> slot (t+1)&1,
// last read by tile t-1, same argument. No inner barriers (gemmQ's thin
// phases regressed in R9; this keeps the fat single-window body).
//   gemm1: <8,3> LDS 136KB, grid 16x16 = 256 blocks (full fill).
//   gemm2: <4,4> LDS 128KB, grid  8x32 = 256 blocks (full fill).
template<int MI, int NIW>
__global__ __launch_bounds__(512, 2)
void gemmS(const bf16* __restrict__ A, const bf16* __restrict__ W,
           void* __restrict__ C, int M, int N, int K, int lda,
           int oGate, const int* __restrict__ flagp)
{
    constexpr int BM     = MI * 32;
    constexpr int BN     = NIW * 64;
    constexpr int ABYTES = BM * 128;        // bytes per A K-tile (BK=64 bf16)
    constexpr int BBYTES = BN * 128;        // bytes per B K-tile
    constexpr int AUL    = BM / 64;         // gld16 per thread for A
    constexpr int BUL    = BN / 64;         // gld16 per thread for B

    __shared__ __bf16 As[2][BM][64];
    __shared__ __bf16 Bs[3][BN][64];

    const bool oF = oGate && (*flagp != 0);

    // XCD swizzle: hardware slot lin -> logical tile swz (bijective, nwg%8==0)
    const int gx  = gridDim.x;
    const int lin = blockIdx.y * gx + blockIdx.x;
    const int cpx = (gx * gridDim.y) >> 3;
    const int swzid = (lin & 7) * cpx + (lin >> 3);
    const int bx = swzid % gx;
    const int by = swzid / gx;

    const int tid   = threadIdx.x;
    const int lane  = tid & 63;
    const int wid   = tid >> 6;
    const int row16 = lane & 15;
    const int quad  = lane >> 4;
    const int wr    = wid >> 2;          // 0..1
    const int wc    = wid & 3;           // 0..3
    const int m0    = by * BM;
    const int n0    = bx * BN;
    const int NT    = K >> 6;            // 64-wide K-tiles

    const int srow = tid >> 3;                        // 0..63
    const int sc8  = ((tid & 7) ^ (srow & 7)) * 8;    // element offset
    const bf16* Ag = A + (size_t)(m0 + srow) * lda + sc8;
    const bf16* Bg = W + (size_t)(n0 + srow) * K   + sc8;
    char* const AsB = (char*)As;
    char* const BsB = (char*)Bs;
    const int sdst = tid * 16;

    auto stA = [&](int kt, int s) {
#pragma unroll
        for (int u = 0; u < AUL; ++u)
            gld16(Ag + (size_t)(u * 64) * lda + kt * 64,
                  AsB + s * ABYTES + u * 8192 + sdst);
    };
    auto stB = [&](int kt, int s) {
#pragma unroll
        for (int u = 0; u < BUL; ++u)
            gld16(Bg + (size_t)(u * 64) * K + kt * 64,
                  BsB + s * BBYTES + u * 8192 + sdst);
    };

    const int swz  = ((quad ^ (row16 & 7)) * 16);          // kk=0
    const int swz1 = (((4 + quad) ^ (row16 & 7)) * 16);    // kk=1
    const int aRow = wr * (MI * 16) + row16;
    const int bRow = wc * (NIW * 16) + row16;

    auto ldA = [&](int sb, int mi, int kk) -> bf16x8 {
        return *(const bf16x8*)(AsB + sb + (aRow + mi * 16) * 128
                                + (kk ? swz1 : swz));
    };
    auto ldB = [&](int sb, int ni, int kk) -> bf16x8 {
        return *(const bf16x8*)(BsB + sb + (bRow + ni * 16) * 128
                                + (kk ? swz1 : swz));
    };

    f32x4 acc[MI][NIW];
#pragma unroll
    for (int i = 0; i < MI; i++)
#pragma unroll
        for (int j = 0; j < NIW; j++)
            acc[i][j] = (f32x4){0.f, 0.f, 0.f, 0.f};

    // prologue: A0->slot0, B0->slot0, B1->slot1; drain A0,B0 (leave B1)
    stA(0, 0); stB(0, 0); stB(1, 1);
    if constexpr (BUL == 3) asm volatile("s_waitcnt vmcnt(3)" ::: "memory");
    else                    asm volatile("s_waitcnt vmcnt(4)" ::: "memory");
    __builtin_amdgcn_s_barrier();
    __builtin_amdgcn_sched_barrier(0);

    for (int t = 0; t < NT; ++t) {
        const int sbA = (t & 1) * ABYTES;
        const int sbB = (t % 3) * BBYTES;

        bf16x8 bfr[NIW][2];
#pragma unroll
        for (int ni = 0; ni < NIW; ni++)
#pragma unroll
            for (int kk = 0; kk < 2; kk++)
                bfr[ni][kk] = ldB(sbB, ni, kk);
        bf16x8 a0[2][2];
#pragma unroll
        for (int i = 0; i < 2; i++)
#pragma unroll
            for (int kk = 0; kk < 2; kk++)
                a0[i][kk] = ldA(sbA, i, kk);

        // stage: A(t+1) first (older), then B(t+2) (newest BUL)
        if (t + 1 < NT) stA(t + 1, (t + 1) & 1);
        if (t + 2 < NT) stB(t + 2, (t + 2) % 3);

        __builtin_amdgcn_s_setprio(1);
#pragma unroll
        for (int kk = 0; kk < 2; kk++)
#pragma unroll
            for (int i = 0; i < 2; i++)
#pragma unroll
                for (int ni = 0; ni < NIW; ni++)
                    acc[i][ni] = MFMA16(a0[i][kk], bfr[ni][kk], acc[i][ni]);
        __builtin_amdgcn_s_setprio(0);

#pragma unroll
        for (int p = 1; p < MI / 2; ++p) {
            bf16x8 ap[2][2];
#pragma unroll
            for (int i = 0; i < 2; i++)
#pragma unroll
                for (int kk = 0; kk < 2; kk++)
                    ap[i][kk] = ldA(sbA, 2 * p + i, kk);
            __builtin_amdgcn_s_setprio(1);
#pragma unroll
            for (int kk = 0; kk < 2; kk++)
#pragma unroll
                for (int i = 0; i < 2; i++)
#pragma unroll
                    for (int ni = 0; ni < NIW; ni++)
                        acc[2 * p + i][ni] =
                            MFMA16(ap[i][kk], bfr[ni][kk], acc[2 * p + i][ni]);
            __builtin_amdgcn_s_setprio(0);
        }

        // counted end-of-tile wait: leave only B(t+2) in flight
        if (t + 2 < NT) {
            if constexpr (BUL == 3) asm volatile("s_waitcnt vmcnt(3)" ::: "memory");
            else                    asm volatile("s_waitcnt vmcnt(4)" ::: "memory");
        } else {
            asm volatile("s_waitcnt vmcnt(0)" ::: "memory");
        }
        __builtin_amdgcn_s_barrier();
        __builtin_amdgcn_sched_barrier(0);
    }

#pragma unroll
    for (int mi = 0; mi < MI; mi++) {
        int rowb = m0 + wr * (MI * 16) + mi * 16 + quad * 4;
#pragma unroll
        for (int ni = 0; ni < NIW; ni++) {
            int col = n0 + wc * (NIW * 16) + ni * 16 + row16;
#pragma unroll
            for (int r = 0; r < 4; r++) {
                size_t idx = (size_t)(rowb + r) * N + col;
                float  v   = acc[mi][ni][r];
                if (oF) ((float*)C)[idx] = v;
                else    ((bf16*)C)[idx]  = __float2bfloat16(v);
            }
        }
    }
}

// ---------------------------------------------------------------------------
// R12: fused vtrans + rope_rms (one launch; disjoint qkv regions, block-
// uniform branch). Blocks [0,20480): rope on q,k (cols 0..2559).
// Blocks [20480,20736): LDS-tiled V transpose (cols 2560+ -> vt).
__global__ __launch_bounds__(256)
void vtrans_rope(bf16* __restrict__ qkv, bf16* __restrict__ vt,
                 const void* __restrict__ cosp, const void* __restrict__ sinp,
                 const int* __restrict__ flagp)
{
    __shared__ __bf16 tl[64][136];
    const int tid = threadIdx.x;

    if (blockIdx.x < 20480) {
        // ---- rope_rms (verified body) ----
        const bool f = *flagp != 0;
        const int wg   = blockIdx.x * 4 + (tid >> 6);
        const int lane = tid & 63;
        const int s    = wg % 20;
        const int m    = wg / 20;
        const int t    = m & (TSEQ - 1);

        const int col = (s < 16) ? s * HD : CE + (s - 16) * HD;
        bf16* p = qkv + (size_t)m * NQKV + col;

        float xlo = __bfloat162float(p[lane]);
        float xhi = __bfloat162float(p[lane + 64]);
        float cl  = ldf(cosp, t * HD + lane, f);
        float sl  = ldf(sinp, t * HD + lane, f);
        float ch  = ldf(cosp, t * HD + 64 + lane, f);
        float sh  = ldf(sinp, t * HD + 64 + lane, f);

        float rlo = xlo * cl - xhi * sl;
        float rhi = xhi * ch + xlo * sh;

        float ss = rlo * rlo + rhi * rhi;
#pragma unroll
        for (int off = 32; off > 0; off >>= 1)
            ss += __shfl_xor(ss, off, 64);
        float inv = rsqrtf(ss * (1.0f / 128.0f) + 1.1920929e-07f);
        if (s < 16) inv *= QSCALE;

        p[lane]      = __float2bfloat16(rlo * inv);
        p[lane + 64] = __float2bfloat16(rhi * inv);
    } else {
        // ---- vtrans (verified body) ----
        const int bi  = blockIdx.x - 20480;
        const int bh  = bi >> 5;              // 0..7 = b*4+hk
        const int t0  = (bi & 31) * 64;
        const int b   = bh >> 2;
        const int hk  = bh & 3;

        const bf16* src = qkv + ((size_t)(b * TSEQ + t0)) * NQKV + 2560 + hk * HD;
#pragma unroll
        for (int it = 0; it < 4; ++it) {
            int idx  = it * 256 + tid;
            int trow = idx >> 4;
            int dcol = (idx & 15) * 8;
            *(uint4*)&tl[trow][dcol] = *(const uint4*)(src + (size_t)trow * NQKV + dcol);
        }
        __syncthreads();

        bf16* dst = vt + ((size_t)(bh * HD)) * TSEQ + t0;
#pragma unroll
        for (int it = 0; it < 4; ++it) {
            int idx  = it * 256 + tid;
            int drow = idx >> 3;
            int tcol = (idx & 7) * 8;
            bf16x8 v;
#pragma unroll
            for (int j = 0; j < 8; ++j)
                v[j] = tl[tcol + j][drow];
            *(bf16x8*)(dst + (size_t)drow * TSEQ + tcol) = v;
        }
    }
}

// ---------------------------------------------------------------------------
// Flash attention (unchanged, verified R10): 2-heads/wave + key-split.
__global__ __launch_bounds__(512, 2)
void attn(bf16* __restrict__ qkv, const bf16* __restrict__ vt)
{
    __shared__ char lds[81920];
    char* const KsB = lds;             // 2 x 16KB K tiles (swizzled image)
    char* const VsB = lds + 32768;     // 2 x 16KB V tiles (swizzled image)
    char* const PlB = lds + 65536;     // 16KB: per-wave P [wid][h2][16][32]

    const int tid   = threadIdx.x;
    const int lane  = tid & 63;
    const int wid   = tid >> 6;
    const int row16 = lane & 15;
    const int quad  = lane >> 4;
    const int b   = blockIdx.y >> 2;
    const int hk  = blockIdx.y & 3;
    const int hp  = wid & 1;              // head-pair within hk group
    const int mh  = (wid >> 1) & 1;       // 16-row half of the 32-row tile
    const int ks  = wid >> 2;             // 32-key half
    const int h0  = hk * 4 + hp * 2;      // first of the wave's two heads
    const int p   = blockIdx.x;           // 0..31

    const bf16* Kp = qkv + ((size_t)(b * TSEQ)) * NQKV + CE + hk * HD;
    const bf16* Vp = vt + ((size_t)(b * 4 + hk) * HD) * TSEQ;

    auto stage = [&](int buf, int k0) {
#pragma unroll
        for (int i = 0; i < 2; i++) {
            int kr = (wid << 3) + i * 4 + (lane >> 4);
            int kc = (lane & 15) ^ (kr & 7);
            gld16(Kp + (size_t)(k0 + kr) * NQKV + kc * 8,
                  KsB + buf * 16384 + ((wid << 3) + i * 4) * 256 + lane * 16);
            int vr = (wid << 4) + i * 8 + (lane >> 3);
            int vc = (lane & 7) ^ (vr & 7);
            gld16(Vp + (size_t)vr * TSEQ + k0 + vc * 8,
                  VsB + buf * 16384 + ((wid << 4) + i * 8) * 128 + lane * 16);
        }
    };

    for (int pass = 0; pass < 2; ++pass) {
        const int xi  = pass ? 63 - p : p;     // 32-row q-tile index 0..63
        const int nkt = (xi >> 1) + 1;         // causal k-tiles (64-wide)
        const int qr0 = xi * 32 + mh * 16;     // wave's first q row

        const bf16* Q = qkv + ((size_t)(b * TSEQ + qr0)) * NQKV + h0 * HD;
        bf16x8 aq[2][4];
#pragma unroll
        for (int h2 = 0; h2 < 2; h2++)
#pragma unroll
            for (int ds = 0; ds < 4; ds++)
                aq[h2][ds] = *(const bf16x8*)(Q + h2 * HD
                             + (size_t)row16 * NQKV + ds * 32 + quad * 8);

        f32x4 o[2][8];
#pragma unroll
        for (int h2 = 0; h2 < 2; h2++)
#pragma unroll
            for (int dt = 0; dt < 8; dt++)
                o[h2][dt] = (f32x4){0.f, 0.f, 0.f, 0.f};
        f32x4 lsum[2] = {(f32x4){0.f,0.f,0.f,0.f}, (f32x4){0.f,0.f,0.f,0.f}};

        __syncthreads();          // prior pass's scratch reads complete
        stage(0, 0);
        __syncthreads();          // tile 0 landed

        for (int t = 0; t < nkt; ++t) {
            const int cur = t & 1;
            if (t + 1 < nkt) stage(cur ^ 1, (t + 1) * 64);   // prefetch

            // QK^T: 8 kf reads feed 16 MFMA (2 heads)
            f32x4 s[2][2];
#pragma unroll
            for (int h2 = 0; h2 < 2; h2++)
#pragma unroll
                for (int kgl = 0; kgl < 2; kgl++)
                    s[h2][kgl] = (f32x4){0.f, 0.f, 0.f, 0.f};
            __builtin_amdgcn_s_setprio(1);
#pragma unroll
            for (int ds = 0; ds < 4; ds++) {
#pragma unroll
                for (int kgl = 0; kgl < 2; kgl++) {
                    int krow = (ks * 2 + kgl) * 16 + row16;
                    int phys = (ds * 4 + quad) ^ (krow & 7);
                    bf16x8 kf = *(const bf16x8*)(KsB + cur * 16384
                                                 + krow * 256 + phys * 16);
                    s[0][kgl] = MFMA16(aq[0][ds], kf, s[0][kgl]);
                    s[1][kgl] = MFMA16(aq[1][ds], kf, s[1][kgl]);
                }
            }
            __builtin_amdgcn_s_setprio(0);

            const bool diag = (t == nkt - 1);
            const int  kbase = t * 64 + ks * 32;
            const int  r16h = row16 >> 3;
            const int  r16l = (row16 & 7) * 2;
#pragma unroll
            for (int h2 = 0; h2 < 2; h2++) {
#pragma unroll
                for (int r = 0; r < 4; r++) {
                    int prow = quad * 4 + r;
                    int qrow = qr0 + prow;
                    float pv0, pv1;
                    {
                        float e0 = __builtin_amdgcn_exp2f(s[h2][0][r] - M2);
                        float e1 = __builtin_amdgcn_exp2f(s[h2][1][r] - M2);
                        pv0 = (!diag || (kbase + row16      <= qrow)) ? e0 : 0.f;
                        pv1 = (!diag || (kbase + 16 + row16 <= qrow)) ? e1 : 0.f;
                    }
                    lsum[h2][r] += pv0 + pv1;
                    char* base = PlB + wid * 2048 + h2 * 1024 + prow * 64;
                    *(__bf16*)(base + (((0 * 2 + r16h) ^ (prow & 3)) << 4) + r16l)
                        = (__bf16)pv0;
                    *(__bf16*)(base + (((1 * 2 + r16h) ^ (prow & 3)) << 4) + r16l)
                        = (__bf16)pv1;
                }
            }
            __asm__ volatile("" ::: "memory");

            // PV (this wave's key half): 2 pf + 8 vf reads feed 16 MFMA
            __builtin_amdgcn_s_setprio(1);
            bf16x8 pf0 = *(const bf16x8*)(PlB + wid * 2048 + row16 * 64
                                          + ((quad ^ (row16 & 3)) << 4));
            bf16x8 pf1 = *(const bf16x8*)(PlB + wid * 2048 + 1024 + row16 * 64
                                          + ((quad ^ (row16 & 3)) << 4));
#pragma unroll
            for (int dt = 0; dt < 8; dt++) {
                int vrow = dt * 16 + row16;
                int phys = (ks * 4 + quad) ^ (vrow & 7);
                bf16x8 vf = *(const bf16x8*)(VsB + cur * 16384
                                             + vrow * 128 + phys * 16);
                o[0][dt] = MFMA16(pf0, vf, o[0][dt]);
                o[1][dt] = MFMA16(pf1, vf, o[1][dt]);
            }
            __builtin_amdgcn_s_setprio(0);
            __asm__ volatile("" ::: "memory");
            __syncthreads();   // reads of `cur` done; prefetch landed
        }

        // ---- pass-end: combine ks halves, then write O ----
        const int g = (hp << 1) | mh;         // 0..3
        char* const scr = lds + g * 16384;    // 16KB per group in Ks/Vs region
        __syncthreads();                      // K/V tiles dead; scratch safe
        if (ks) {
#pragma unroll
            for (int h2 = 0; h2 < 2; h2++)
#pragma unroll
                for (int dt = 0; dt < 8; dt++)
                    *(f32x4*)(scr + (h2 * 8 + dt) * 1024 + lane * 16) = o[h2][dt];
            *(f32x4*)(PlB + g * 4096 + lane * 32)      = lsum[0];
            *(f32x4*)(PlB + g * 4096 + lane * 32 + 16) = lsum[1];
        }
        __syncthreads();
        if (!ks) {
#pragma unroll
            for (int h2 = 0; h2 < 2; h2++)
#pragma unroll
                for (int dt = 0; dt < 8; dt++)
                    o[h2][dt] += *(const f32x4*)(scr + (h2 * 8 + dt) * 1024
                                                 + lane * 16);
            f32x4 l0 = *(const f32x4*)(PlB + g * 4096 + lane * 32);
            f32x4 l1 = *(const f32x4*)(PlB + g * 4096 + lane * 32 + 16);
#pragma unroll
            for (int h2 = 0; h2 < 2; h2++) {
#pragma unroll
                for (int r = 0; r < 4; r++) {
                    float l = lsum[h2][r] + (h2 ? l1[r] : l0[r]);
#pragma unroll
                    for (int off = 1; off < 16; off <<= 1)
                        l += __shfl_xor(l, off, 64);
                    float rl = 1.0f / l;
                    int trow = qr0 + quad * 4 + r;
                    bf16* dst = qkv + ((size_t)(b * TSEQ + trow)) * NQKV
                                + (h0 + h2) * HD;
#pragma unroll
                    for (int dt = 0; dt < 8; dt++)
                        dst[dt * 16 + row16] = __float2bfloat16(o[h2][dt][r] * rl);
                }
            }
        }
    }
}

// ---------------------------------------------------------------------------
extern "C" void kernel_launch(void* const* d_in, const int* in_sizes, int n_in,
                              void* d_out, int out_size, void* d_ws, size_t ws_size,
                              hipStream_t stream)
{
    // ws (bf16 elems): qkv [4096,3072] 25.2MB | vt 4.2MB | wqkvb [3072,2048]
    // 12.6MB (reused for wprojb after gemm1) | flag | xb [4096,2048] 16.8MB.
    bf16* qkv   = (bf16*)d_ws;
    bf16* vt    = qkv + (size_t)BT * NQKV;
    bf16* wqkvb = vt + (size_t)2 * 4 * HD * TSEQ;
    int* flagp  = (int*)(wqkvb + (size_t)NQKV * CE);
    bf16* xb    = wqkvb + (size_t)NQKV * CE + 16;   // 32B after flag, 16B-aligned

    const size_t need = ((size_t)BT * NQKV + (size_t)2 * 4 * HD * TSEQ
                         + (size_t)NQKV * CE + 16 + (size_t)BT * CE) * sizeof(bf16);
    const bool useXb = ws_size >= need;

    // 0) detect input dtype -> device flag
    detect_dtype<<<1, 256, 0, stream>>>((const unsigned short*)d_in[0], flagp);

    // 1) fused conversion: wq/wk/wv (+x when useXb) in ONE launch
    conv_all<<<useXb ? 7168 : 3072, 256, 0, stream>>>(
        d_in[3], d_in[4], d_in[5], d_in[0], wqkvb, xb, flagp);

    // 2) fused QKV projection: gemmS<8,3> 16x16 = 256 blocks (full fill)
    if (useXb) {
        gemmS<8, 3><<<dim3(NQKV / 192, BT / 256), 512, 0, stream>>>(
            xb, wqkvb, qkv, BT, NQKV, CE, CE, 0, flagp);
    } else {
        gemm_bt<<<dim3(NQKV / 128, BT / 128), 256, 0, stream>>>(
            d_in[0], wqkvb, qkv, BT, NQKV, CE, CE, 1, 0, flagp);
    }

    // 3) convert wproj into the same buffer (stream-ordered after gemm1)
    conv_bf16<<<(2048 * 2048 / 8) / 256, 256, 0, stream>>>(d_in[6], wqkvb, flagp);

    // 4+5) fused V-transpose + RoPE/RMSNorm (one launch)
    vtrans_rope<<<20736, 256, 0, stream>>>(qkv, vt, d_in[1], d_in[2], flagp);

    // 6) balanced GQA-fused flash attention; O overwrites qkv's Q columns
    attn<<<dim3(32, 2 * 4), 512, 0, stream>>>(qkv, vt);

    // 7) output projection: gemmS<4,4> 8x32 = 256 blocks (full fill)
    if (useXb) {
        gemmS<4, 4><<<dim3(CE / 256, BT / 128), 512, 0, stream>>>(
            qkv, wqkvb, d_out, BT, CE, CE, NQKV, 1, flagp);
    } else {
        gemm_bt<<<dim3(CE / 128, BT / 128), 256, 0, stream>>>(
            qkv, wqkvb, d_out, BT, CE, CE, NQKV, 0, 1, flagp);
    }
}